// Round 3
// baseline (333.297 us; speedup 1.0000x reference)
//
#include <hip/hip_runtime.h>
#include <hip/hip_bf16.h>
#include <math.h>

typedef __hip_bfloat16 bf16;
typedef __bf16 bf16x8 __attribute__((ext_vector_type(8)));
typedef float floatx4 __attribute__((ext_vector_type(4)));

#define LOG2E 1.44269504088896340736f
#define DINNER 2048
#define NCHUNK 32
#define CLEN 32   // SEQ / NCHUNK

static __device__ __forceinline__ void gl_lds16(const void* g, void* l) {
  __builtin_amdgcn_global_load_lds(
      (const __attribute__((address_space(1))) void*)g,
      (__attribute__((address_space(3))) void*)l, 16, 0, 0);
}

// ---------------- dtype sniffer: 1 = fp32 input buffers, 0 = bf16 ----------------
__global__ void sniff(const void* __restrict__ x, int* __restrict__ flag) {
  __shared__ int cnt;
  if (threadIdx.x == 0) cnt = 0;
  __syncthreads();
  const unsigned* w = (const unsigned*)x;
  int c = 0;
  for (int i = threadIdx.x; i < 1024; i += 256) {
    unsigned e = (w[i] >> 23) & 0xFF;   // fp32 exponent field
    if (e >= 112 && e <= 142) c++;      // |v| in [2^-15, 2^15] -> N(0,1) fp32 data
  }
  atomicAdd(&cnt, c);
  __syncthreads();
  if (threadIdx.x == 0) *flag = (cnt >= 512) ? 1 : 0;
}

__global__ void cvt_to_bf16(const int* __restrict__ flag, const void* __restrict__ src,
                            bf16* __restrict__ dst, int n) {
  int g = blockIdx.x * 256 + threadIdx.x;
  if (g >= n) return;
  if (*flag) dst[g] = __float2bfloat16(((const float*)src)[g]);
  else       dst[g] = ((const bf16*)src)[g];
}
__global__ void cvt_to_f32(const int* __restrict__ flag, const void* __restrict__ src,
                           float* __restrict__ dst, int n) {
  int g = blockIdx.x * 256 + threadIdx.x;
  if (g >= n) return;
  if (*flag) dst[g] = ((const float*)src)[g];
  else       dst[g] = __bfloat162float(((const bf16*)src)[g]);
}
__global__ void zero_f32(float* __restrict__ p, int n) {
  int g = blockIdx.x * 256 + threadIdx.x;
  if (g < n) p[g] = 0.f;
}

// ---------------- transpose + convert: dst[C][R](bf16) = src[R][C] ----------------
__global__ void transpose_any(const int* __restrict__ flag, const void* __restrict__ src,
                              bf16* __restrict__ dst, int R, int C) {
  __shared__ bf16 tile[32][33];
  bool f = *flag;
  int c0 = blockIdx.x * 32, r0 = blockIdx.y * 32;
  int tx = threadIdx.x, ty = threadIdx.y;      // block (32,8)
#pragma unroll
  for (int i = 0; i < 4; i++) {
    size_t idx = (size_t)(r0 + ty + i * 8) * C + c0 + tx;
    tile[ty + i * 8][tx] = f ? __float2bfloat16(((const float*)src)[idx])
                             : ((const bf16*)src)[idx];
  }
  __syncthreads();
#pragma unroll
  for (int i = 0; i < 4; i++)
    dst[(size_t)(c0 + ty + i * 8) * R + r0 + tx] = tile[tx][ty + i * 8];
}

// ---------------- 128x128 MFMA GEMM, A: MxK rowmajor, Bt: NxK rowmajor ----------------
// flags: 1 = softplus(+bias) epilogue, 4 = atomicAdd fp32 (split-K)
__global__ __launch_bounds__(256, 2)
void gemm128(const bf16* __restrict__ A, const bf16* __restrict__ Bt,
             int M, int N, int K, int lda, int ldb, int ksplit,
             float* __restrict__ outF, bf16* __restrict__ outB,
             const float* __restrict__ bias, int flags) {
  __shared__ bf16 As[128 * 32];
  __shared__ bf16 Bs[128 * 32];
  const int tid = threadIdx.x;
  const int wave = tid >> 6, lane = tid & 63;
  const int wm = wave & 1, wn = wave >> 1;
  const int m0 = blockIdx.y * 128, n0 = blockIdx.x * 128;
  const int kper = K / ksplit;
  const int kbeg = blockIdx.z * kper, kend = kbeg + kper;

  floatx4 acc[4][4];
#pragma unroll
  for (int i = 0; i < 4; i++)
#pragma unroll
    for (int j = 0; j < 4; j++) acc[i][j] = (floatx4){0.f, 0.f, 0.f, 0.f};

  const int ch0 = wave * 2, ch1 = wave * 2 + 1;
  const int srow = lane >> 2;         // 0..15
  const int skcol = (lane & 3) * 8;   // 0,8,16,24
  const int fr = lane & 15, quad = lane >> 4;

  for (int k0 = kbeg; k0 < kend; k0 += 32) {
    __syncthreads();
    {
      int ra0 = m0 + ch0 * 16 + srow;
      int ra1 = m0 + ch1 * 16 + srow;
      gl_lds16(A + (size_t)ra0 * lda + k0 + skcol, (char*)As + ch0 * 1024 + lane * 16);
      gl_lds16(A + (size_t)ra1 * lda + k0 + skcol, (char*)As + ch1 * 1024 + lane * 16);
      int rb0 = n0 + ch0 * 16 + srow; if (rb0 > N - 1) rb0 = N - 1;  // clamp (N=96 case)
      int rb1 = n0 + ch1 * 16 + srow; if (rb1 > N - 1) rb1 = N - 1;
      gl_lds16(Bt + (size_t)rb0 * ldb + k0 + skcol, (char*)Bs + ch0 * 1024 + lane * 16);
      gl_lds16(Bt + (size_t)rb1 * ldb + k0 + skcol, (char*)Bs + ch1 * 1024 + lane * 16);
    }
    __syncthreads();
    bf16x8 af[4], bfr[4];
#pragma unroll
    for (int i = 0; i < 4; i++)
      af[i] = *reinterpret_cast<const bf16x8*>(&As[(wm * 64 + i * 16 + fr) * 32 + quad * 8]);
#pragma unroll
    for (int j = 0; j < 4; j++)
      bfr[j] = *reinterpret_cast<const bf16x8*>(&Bs[(wn * 64 + j * 16 + fr) * 32 + quad * 8]);
#pragma unroll
    for (int i = 0; i < 4; i++)
#pragma unroll
      for (int j = 0; j < 4; j++)
        acc[i][j] = __builtin_amdgcn_mfma_f32_16x16x32_bf16(af[i], bfr[j], acc[i][j], 0, 0, 0);
  }

  // epilogue: C/D layout col=lane&15, row=quad*4+r
#pragma unroll
  for (int i = 0; i < 4; i++) {
#pragma unroll
    for (int j = 0; j < 4; j++) {
      int col = n0 + wn * 64 + j * 16 + fr;
      if (col >= N) continue;
#pragma unroll
      for (int r = 0; r < 4; r++) {
        int row = m0 + wm * 64 + i * 16 + quad * 4 + r;
        float v = acc[i][j][r];
        if (flags & 4) {
          atomicAdd(&outF[(size_t)row * N + col], v);
        } else {
          if (bias) v += bias[col];
          if (flags & 1) v = (v > 20.f) ? v : log1pf(expf(v));  // softplus
          if (outF) outF[(size_t)row * N + col] = v;
          if (outB) outB[(size_t)row * N + col] = __float2bfloat16(v);
        }
      }
    }
  }
  (void)M;
}

// ---------------- causal depthwise conv (k=4) + bias + SiLU ----------------
// reads u-half of xzb (bf16, ld 4096), writes u bf16 (ld 2048)
__global__ void conv_silu(const bf16* __restrict__ xzb, const float* __restrict__ ck,
                          const float* __restrict__ cb, bf16* __restrict__ u) {
  int d = blockIdx.x * 256 + threadIdx.x;
  int r0 = blockIdx.y * 8;          // 8 rows per block-row; 1024%8==0 so no batch crossing
  int t0 = r0 & 1023;
  float k0 = ck[0 * DINNER + d];
  float k1 = ck[1 * DINNER + d];
  float k2 = ck[2 * DINNER + d];
  float k3 = ck[3 * DINNER + d];
  float bias = cb[d];
  float in[11];
#pragma unroll
  for (int i = 0; i < 11; i++) {
    int t = t0 - 3 + i;
    in[i] = (t >= 0) ? __bfloat162float(xzb[(size_t)(r0 - 3 + i) * 4096 + d]) : 0.f;
  }
#pragma unroll
  for (int i = 0; i < 8; i++) {
    float v = bias + in[i] * k0 + in[i + 1] * k1 + in[i + 2] * k2 + in[i + 3] * k3;
    v = v / (1.f + expf(-v));       // SiLU
    u[(size_t)(r0 + i) * DINNER + d] = __float2bfloat16(v);
  }
}

__global__ void cvt_dt(const float* __restrict__ xdbl, bf16* __restrict__ dt) {
  int g = blockIdx.x * 256 + threadIdx.x;   // 2048*64
  int r = g >> 6, j = g & 63;
  dt[g] = __float2bfloat16(xdbl[(size_t)r * 96 + j]);
}

__global__ void cvt_out_any(const int* __restrict__ flag, const float* __restrict__ t,
                            void* __restrict__ out, int n) {
  int g = blockIdx.x * 256 + threadIdx.x;
  if (g >= n) return;
  if (*flag) ((float*)out)[g] = t[g];
  else       ((bf16*)out)[g] = __float2bfloat16(t[g]);
}

// ---------------- scan phase A: per-chunk local h_end + sum(delta) ----------------
__global__ void scanA(const bf16* __restrict__ delta, const bf16* __restrict__ u,
                      const float* __restrict__ xdbl, const float* __restrict__ A_log,
                      float* __restrict__ hend, float* __restrict__ Ssum) {
  int d = blockIdx.x * 256 + threadIdx.x;
  int c = blockIdx.y, b = blockIdx.z;
  float al2e[16];
#pragma unroll
  for (int n = 0; n < 16; n++)
    al2e[n] = -expf(A_log[d * 16 + n]) * LOG2E;
  float h[16];
#pragma unroll
  for (int n = 0; n < 16; n++) h[n] = 0.f;
  float S = 0.f;
  int t0 = c * CLEN;
  for (int t = t0; t < t0 + CLEN; ++t) {
    int r = b * 1024 + t;
    float dt = __bfloat162float(delta[(size_t)r * DINNER + d]);
    float ut = __bfloat162float(u[(size_t)r * DINNER + d]);
    float du = dt * ut;
    S += dt;
    const float* bc = xdbl + (size_t)r * 96 + 64;   // wave-uniform -> scalar loads
#pragma unroll
    for (int n = 0; n < 16; n++) {
      float dA = exp2f(dt * al2e[n]);
      h[n] = dA * h[n] + du * bc[n];
    }
  }
  size_t base = (((size_t)(b * NCHUNK + c) * DINNER) + d) * 16;
#pragma unroll
  for (int n = 0; n < 16; n++) hend[base + n] = h[n];
  Ssum[(b * NCHUNK + c) * DINNER + d] = S;
}

// ---------------- scan phase B: cross-chunk recurrence, Hin IN PLACE over hend ---------
__global__ void scanB(float* __restrict__ hend, const float* __restrict__ Ssum,
                      const float* __restrict__ A_log) {
  int g = blockIdx.x * 256 + threadIdx.x;   // 2*2048*16
  int n = g & 15, d = (g >> 4) & 2047, b = g >> 15;
  float al2e = -expf(A_log[d * 16 + n]) * LOG2E;
  float H = 0.f;
#pragma unroll
  for (int c = 0; c < NCHUNK; c++) {
    size_t idx = (((size_t)(b * NCHUNK + c) * DINNER) + d) * 16 + n;
    float he = hend[idx];
    float P = exp2f(Ssum[(b * NCHUNK + c) * DINNER + d] * al2e);
    hend[idx] = H;                                   // now holds H_in for chunk c
    H = P * H + he;
  }
}

// ---------------- scan phase C: full scan w/ correct h0, fused skip+gate ----------------
// writes yg into the (dead) u-preact half of xzb: yg[r*4096 + d]
__global__ void scanC(const bf16* __restrict__ delta, const bf16* __restrict__ u,
                      const float* __restrict__ xdbl, const bf16* __restrict__ xzb,
                      const float* __restrict__ A_log, const float* __restrict__ Dv,
                      const float* __restrict__ Hin, bf16* __restrict__ yg) {
  int d = blockIdx.x * 256 + threadIdx.x;
  int c = blockIdx.y, b = blockIdx.z;
  float al2e[16];
#pragma unroll
  for (int n = 0; n < 16; n++)
    al2e[n] = -expf(A_log[d * 16 + n]) * LOG2E;
  float Dd = Dv[d];
  float h[16];
  size_t hb = (((size_t)(b * NCHUNK + c) * DINNER) + d) * 16;
#pragma unroll
  for (int n = 0; n < 16; n++) h[n] = Hin[hb + n];
  int t0 = c * CLEN;
  for (int t = t0; t < t0 + CLEN; ++t) {
    int r = b * 1024 + t;
    float dt = __bfloat162float(delta[(size_t)r * DINNER + d]);
    float ut = __bfloat162float(u[(size_t)r * DINNER + d]);
    float du = dt * ut;
    float z = __bfloat162float(xzb[(size_t)r * 4096 + 2048 + d]);
    const float* bc = xdbl + (size_t)r * 96 + 64;
    float y = 0.f;
#pragma unroll
    for (int n = 0; n < 16; n++) {
      float dA = exp2f(dt * al2e[n]);
      h[n] = dA * h[n] + du * bc[n];
      y += h[n] * bc[16 + n];
    }
    y += ut * Dd;
    y *= z / (1.f + expf(-z));                     // * silu(z)
    yg[(size_t)r * 4096 + d] = __float2bfloat16(y);
  }
}

extern "C" void kernel_launch(void* const* d_in, const int* in_sizes, int n_in,
                              void* d_out, int out_size, void* d_ws, size_t ws_size,
                              hipStream_t stream) {
  const void* x     = d_in[0];
  const void* W_in  = d_in[1];
  const void* ck    = d_in[2];
  const void* cb    = d_in[3];
  const void* W_x   = d_in[4];
  const void* W_dt  = d_in[5];
  const void* b_dt  = d_in[6];
  const void* W_out = d_in[7];
  const void* A_log = d_in[8];
  const void* Dv    = d_in[9];
  (void)in_sizes; (void)n_in; (void)out_size; (void)ws_size;

  char* w = (char*)d_ws;
  size_t off = 0;
  auto alloc = [&](size_t nb) { void* p = w + off; off += (nb + 255) & ~(size_t)255; return p; };

  int*   flag  = (int*)  alloc(256);
  float* ckF   = (float*)alloc((size_t)4 * 2048 * 4);
  float* cbF   = (float*)alloc((size_t)2048 * 4);
  float* bdtF  = (float*)alloc((size_t)2048 * 4);
  float* AlogF = (float*)alloc((size_t)2048 * 16 * 4);
  float* DF    = (float*)alloc((size_t)2048 * 4);
  bf16*  xb    = (bf16*) alloc((size_t)2048 * 1024 * 2);   // x bf16; reused as WoutT after GEMM1
  bf16*  WinT  = (bf16*) alloc((size_t)4096 * 1024 * 2);   // reused as delta after GEMM1
  bf16*  WxT   = (bf16*) alloc((size_t)96 * 2048 * 2);
  bf16*  WdtT  = (bf16*) alloc((size_t)2048 * 64 * 2);
  bf16*  xzb   = (bf16*) alloc((size_t)2048 * 4096 * 2);   // u-preact half reused as yg
  bf16*  u     = (bf16*) alloc((size_t)2048 * 2048 * 2);
  float* xdbl  = (float*)alloc((size_t)2048 * 96 * 4);
  bf16*  dt    = (bf16*) alloc((size_t)2048 * 64 * 2);
  float* hend  = (float*)alloc((size_t)2 * NCHUNK * 2048 * 16 * 4);  // ->Hin ->otmp
  float* Ssum  = (float*)alloc((size_t)2 * NCHUNK * 2048 * 4);
  // total ~46.5 MB

  bf16*  WoutT = xb;              // alias: dead after GEMM1
  bf16*  delta = WinT;            // alias: dead after GEMM1
  bf16*  yg    = xzb;             // alias: stride 4096, cols 0..2047 (dead after conv)
  float* otmp  = hend;            // alias: dead after scanC

  // --- dtype sniff + input canonicalization ---
  sniff<<<1, 256, 0, stream>>>(x, flag);
  cvt_to_f32<<<32, 256, 0, stream>>>(flag, ck, ckF, 4 * 2048);
  cvt_to_f32<<<8, 256, 0, stream>>>(flag, cb, cbF, 2048);
  cvt_to_f32<<<8, 256, 0, stream>>>(flag, b_dt, bdtF, 2048);
  cvt_to_f32<<<128, 256, 0, stream>>>(flag, A_log, AlogF, 2048 * 16);
  cvt_to_f32<<<8, 256, 0, stream>>>(flag, Dv, DF, 2048);
  cvt_to_bf16<<<8192, 256, 0, stream>>>(flag, x, xb, 2048 * 1024);

  dim3 tb(32, 8);
  transpose_any<<<dim3(128, 32), tb, 0, stream>>>(flag, W_in, WinT, 1024, 4096);
  transpose_any<<<dim3(3, 64),   tb, 0, stream>>>(flag, W_x, WxT, 2048, 96);
  transpose_any<<<dim3(64, 2),   tb, 0, stream>>>(flag, W_dt, WdtT, 64, 2048);

  // GEMM1: xzb = x @ W_in  (bf16 out)
  gemm128<<<dim3(32, 16, 1), 256, 0, stream>>>(xb, WinT, 2048, 4096, 1024, 1024, 1024, 1,
                                               nullptr, xzb, nullptr, 0);
  // W_out^T into the now-dead xb region
  transpose_any<<<dim3(32, 64), tb, 0, stream>>>(flag, W_out, WoutT, 2048, 1024);
  // conv + SiLU -> u (bf16)
  conv_silu<<<dim3(8, 256), 256, 0, stream>>>(xzb, ckF, cbF, u);
  // GEMM2: x_dbl = u @ W_x  (N=96, split-K=16, fp32 atomic)
  zero_f32<<<768, 256, 0, stream>>>(xdbl, 2048 * 96);
  gemm128<<<dim3(1, 16, 16), 256, 0, stream>>>(u, WxT, 2048, 96, 2048, 2048, 2048, 16,
                                               xdbl, nullptr, nullptr, 4);
  cvt_dt<<<512, 256, 0, stream>>>(xdbl, dt);
  // GEMM3: delta = softplus(dt_lo @ W_dt + b_dt)  (bf16 out into dead WinT)
  gemm128<<<dim3(16, 16, 1), 256, 0, stream>>>(dt, WdtT, 2048, 2048, 64, 64, 64, 1,
                                               nullptr, delta, bdtF, 1);
  // chunked selective scan
  scanA<<<dim3(8, NCHUNK, 2), 256, 0, stream>>>(delta, u, xdbl, AlogF, hend, Ssum);
  scanB<<<256, 256, 0, stream>>>(hend, Ssum, AlogF);
  scanC<<<dim3(8, NCHUNK, 2), 256, 0, stream>>>(delta, u, xdbl, xzb, AlogF, DF, hend, yg);
  // GEMM4: out = y_gated @ W_out  (split-K=2, fp32 atomic into dead hend, then cvt)
  zero_f32<<<8192, 256, 0, stream>>>(otmp, 2048 * 1024);
  gemm128<<<dim3(8, 16, 2), 256, 0, stream>>>(yg, WoutT, 2048, 1024, 2048, 4096, 2048, 2,
                                              otmp, nullptr, nullptr, 4);
  cvt_out_any<<<8192, 256, 0, stream>>>(flag, otmp, d_out, 2048 * 1024);
}

// Round 4
// 324.935 us; speedup vs baseline: 1.0257x; 1.0257x over previous
//
#include <hip/hip_runtime.h>
#include <hip/hip_bf16.h>
#include <math.h>

typedef __hip_bfloat16 bf16;
typedef __bf16 bf16x8 __attribute__((ext_vector_type(8)));
typedef float floatx4 __attribute__((ext_vector_type(4)));

#define LOG2E 1.44269504088896340736f
#define DINNER 2048
#define NCHUNK 32
#define CLEN 32   // SEQ / NCHUNK

static __device__ __forceinline__ void gl_lds16(const void* g, void* l) {
  __builtin_amdgcn_global_load_lds(
      (const __attribute__((address_space(1))) void*)g,
      (__attribute__((address_space(3))) void*)l, 16, 0, 0);
}

// ---------------- dtype sniffer: 1 = fp32 input buffers, 0 = bf16 ----------------
__global__ void sniff(const void* __restrict__ x, int* __restrict__ flag) {
  __shared__ int cnt;
  if (threadIdx.x == 0) cnt = 0;
  __syncthreads();
  const unsigned* w = (const unsigned*)x;
  int c = 0;
  for (int i = threadIdx.x; i < 1024; i += 256) {
    unsigned e = (w[i] >> 23) & 0xFF;   // fp32 exponent field
    if (e >= 112 && e <= 142) c++;      // |v| in [2^-15, 2^15] -> N(0,1) fp32 data
  }
  atomicAdd(&cnt, c);
  __syncthreads();
  if (threadIdx.x == 0) *flag = (cnt >= 512) ? 1 : 0;
}

static __device__ __forceinline__ float cvf(const int* flag, const void* s, int i) {
  return *flag ? ((const float*)s)[i] : __bfloat162float(((const bf16*)s)[i]);
}

__global__ void cvt_to_bf16(const int* __restrict__ flag, const void* __restrict__ src,
                            bf16* __restrict__ dst, int n) {
  int g = blockIdx.x * 256 + threadIdx.x;
  if (g >= n) return;
  if (*flag) dst[g] = __float2bfloat16(((const float*)src)[g]);
  else       dst[g] = ((const bf16*)src)[g];
}

// one kernel converts all five small parameter tensors to fp32
__global__ void cvt_params(const int* __restrict__ flag,
                           const void* ck, const void* cb, const void* bdt,
                           const void* Alog, const void* Dv,
                           float* ckF, float* cbF, float* bdtF, float* AlogF, float* DF) {
  int g = blockIdx.x * 256 + threadIdx.x;   // 47104 total
  if (g < 8192)       ckF[g]          = cvf(flag, ck,   g);
  else if (g < 10240) cbF[g - 8192]   = cvf(flag, cb,   g - 8192);
  else if (g < 12288) bdtF[g - 10240] = cvf(flag, bdt,  g - 10240);
  else if (g < 45056) AlogF[g - 12288]= cvf(flag, Alog, g - 12288);
  else if (g < 47104) DF[g - 45056]   = cvf(flag, Dv,   g - 45056);
}

// ---------------- transpose + convert: dst[C][R](bf16) = src[R][C] ----------------
__global__ void transpose_any(const int* __restrict__ flag, const void* __restrict__ src,
                              bf16* __restrict__ dst, int R, int C) {
  __shared__ bf16 tile[32][33];
  bool f = *flag;
  int c0 = blockIdx.x * 32, r0 = blockIdx.y * 32;
  int tx = threadIdx.x, ty = threadIdx.y;      // block (32,8)
#pragma unroll
  for (int i = 0; i < 4; i++) {
    size_t idx = (size_t)(r0 + ty + i * 8) * C + c0 + tx;
    tile[ty + i * 8][tx] = f ? __float2bfloat16(((const float*)src)[idx])
                             : ((const bf16*)src)[idx];
  }
  __syncthreads();
#pragma unroll
  for (int i = 0; i < 4; i++)
    dst[(size_t)(c0 + ty + i * 8) * R + r0 + tx] = tile[tx][ty + i * 8];
}

// ---------------- 128x128 MFMA GEMM, double-buffered LDS ----------------
// A: MxK rowmajor(lda), Bt: NxK rowmajor(ldb)
// flags: 1 = softplus(+bias) epilogue; 8 = partial store outF + z*M*N (split-K slabs)
__global__ __launch_bounds__(256, 2)
void gemm128(const bf16* __restrict__ A, const bf16* __restrict__ Bt,
             int M, int N, int K, int lda, int ldb, int ksplit,
             float* __restrict__ outF, bf16* __restrict__ outB,
             const float* __restrict__ bias, int flags) {
  __shared__ bf16 As[2][128 * 32];
  __shared__ bf16 Bs[2][128 * 32];
  const int tid = threadIdx.x;
  const int wave = tid >> 6, lane = tid & 63;
  const int wm = wave & 1, wn = wave >> 1;
  const int m0 = blockIdx.y * 128, n0 = blockIdx.x * 128;
  const int kper = K / ksplit;
  const int kbeg = blockIdx.z * kper;
  const int niter = kper >> 5;

  floatx4 acc[4][4];
#pragma unroll
  for (int i = 0; i < 4; i++)
#pragma unroll
    for (int j = 0; j < 4; j++) acc[i][j] = (floatx4){0.f, 0.f, 0.f, 0.f};

  const int ch0 = wave * 2, ch1 = wave * 2 + 1;
  const int srow = lane >> 2;         // 0..15
  const int skcol = (lane & 3) * 8;   // 0,8,16,24
  const int fr = lane & 15, quad = lane >> 4;

  // row indices are loop-invariant
  const int ra0 = m0 + ch0 * 16 + srow;
  const int ra1 = m0 + ch1 * 16 + srow;
  int rb0 = n0 + ch0 * 16 + srow; if (rb0 > N - 1) rb0 = N - 1;  // clamp (N=96 case)
  int rb1 = n0 + ch1 * 16 + srow; if (rb1 > N - 1) rb1 = N - 1;

  auto stage = [&](int k0, int p) {
    gl_lds16(A + (size_t)ra0 * lda + k0 + skcol, (char*)As[p] + ch0 * 1024 + lane * 16);
    gl_lds16(A + (size_t)ra1 * lda + k0 + skcol, (char*)As[p] + ch1 * 1024 + lane * 16);
    gl_lds16(Bt + (size_t)rb0 * ldb + k0 + skcol, (char*)Bs[p] + ch0 * 1024 + lane * 16);
    gl_lds16(Bt + (size_t)rb1 * ldb + k0 + skcol, (char*)Bs[p] + ch1 * 1024 + lane * 16);
  };

  stage(kbeg, 0);
  __syncthreads();                       // drain iter-0 staging
  for (int it = 0; it < niter; ++it) {
    const int p = it & 1;
    if (it + 1 < niter) stage(kbeg + (it + 1) * 32, p ^ 1);   // prefetch in flight during MFMA
    bf16x8 af[4], bfr[4];
#pragma unroll
    for (int i = 0; i < 4; i++)
      af[i] = *reinterpret_cast<const bf16x8*>(&As[p][(wm * 64 + i * 16 + fr) * 32 + quad * 8]);
#pragma unroll
    for (int j = 0; j < 4; j++)
      bfr[j] = *reinterpret_cast<const bf16x8*>(&Bs[p][(wn * 64 + j * 16 + fr) * 32 + quad * 8]);
#pragma unroll
    for (int i = 0; i < 4; i++)
#pragma unroll
      for (int j = 0; j < 4; j++)
        acc[i][j] = __builtin_amdgcn_mfma_f32_16x16x32_bf16(af[i], bfr[j], acc[i][j], 0, 0, 0);
    __syncthreads();                     // drains prefetch; LDS safe to swap
  }

  // epilogue: C/D layout col=lane&15, row=quad*4+r
#pragma unroll
  for (int i = 0; i < 4; i++) {
#pragma unroll
    for (int j = 0; j < 4; j++) {
      int col = n0 + wn * 64 + j * 16 + fr;
      if (col >= N) continue;
#pragma unroll
      for (int r = 0; r < 4; r++) {
        int row = m0 + wm * 64 + i * 16 + quad * 4 + r;
        float v = acc[i][j][r];
        if (flags & 8) {
          outF[(size_t)blockIdx.z * M * N + (size_t)row * N + col] = v;
        } else {
          if (bias) v += bias[col];
          if (flags & 1) v = (v > 20.f) ? v : log1pf(expf(v));  // softplus
          if (outF) outF[(size_t)row * N + col] = v;
          if (outB) outB[(size_t)row * N + col] = __float2bfloat16(v);
        }
      }
    }
  }
}

// ---------------- causal depthwise conv (k=4) + bias + SiLU ----------------
__global__ void conv_silu(const bf16* __restrict__ xzb, const float* __restrict__ ck,
                          const float* __restrict__ cb, bf16* __restrict__ u) {
  int d = blockIdx.x * 256 + threadIdx.x;
  int r0 = blockIdx.y * 8;          // 8 rows per block-row; 1024%8==0 so no batch crossing
  int t0 = r0 & 1023;
  float k0 = ck[0 * DINNER + d];
  float k1 = ck[1 * DINNER + d];
  float k2 = ck[2 * DINNER + d];
  float k3 = ck[3 * DINNER + d];
  float bias = cb[d];
  float in[11];
#pragma unroll
  for (int i = 0; i < 11; i++) {
    int t = t0 - 3 + i;
    in[i] = (t >= 0) ? __bfloat162float(xzb[(size_t)(r0 - 3 + i) * 4096 + d]) : 0.f;
  }
#pragma unroll
  for (int i = 0; i < 8; i++) {
    float v = bias + in[i] * k0 + in[i + 1] * k1 + in[i + 2] * k2 + in[i + 3] * k3;
    v = v / (1.f + expf(-v));       // SiLU
    u[(size_t)(r0 + i) * DINNER + d] = __float2bfloat16(v);
  }
}

// ---------------- reduce 16 split-K slabs -> xdbl fp32 + dt bf16 ----------------
__global__ void reduce_xdbl(const float* __restrict__ pb, float* __restrict__ xdbl,
                            bf16* __restrict__ dt) {
  int g = blockIdx.x * 256 + threadIdx.x;   // 2048*96
  if (g >= 2048 * 96) return;
  float s = 0.f;
#pragma unroll
  for (int z = 0; z < 16; z++) s += pb[(size_t)z * 2048 * 96 + g];
  xdbl[g] = s;
  int r = g / 96, j = g - r * 96;
  if (j < 64) dt[r * 64 + j] = __float2bfloat16(s);
}

// ---------------- reduce 2 slabs -> final output in sniffed dtype ----------------
__global__ void reduce_out(const int* __restrict__ flag, const float* __restrict__ pb,
                           void* __restrict__ out) {
  int g = blockIdx.x * 256 + threadIdx.x;   // 2048*1024
  float s = pb[g] + pb[2048 * 1024 + g];
  if (*flag) ((float*)out)[g] = s;
  else       ((bf16*)out)[g] = __float2bfloat16(s);
}

// ---------------- scan phase A: per-chunk local h_end + sum(delta) ----------------
__global__ void scanA(const bf16* __restrict__ delta, const bf16* __restrict__ u,
                      const float* __restrict__ xdbl, const float* __restrict__ A_log,
                      float* __restrict__ hend, float* __restrict__ Ssum) {
  int d = blockIdx.x * 256 + threadIdx.x;
  int c = blockIdx.y, b = blockIdx.z;
  float al2e[16];
#pragma unroll
  for (int n = 0; n < 16; n++)
    al2e[n] = -expf(A_log[d * 16 + n]) * LOG2E;
  float h[16];
#pragma unroll
  for (int n = 0; n < 16; n++) h[n] = 0.f;
  float S = 0.f;
  int t0 = c * CLEN;
  for (int t = t0; t < t0 + CLEN; ++t) {
    int r = b * 1024 + t;
    float dt = __bfloat162float(delta[(size_t)r * DINNER + d]);
    float ut = __bfloat162float(u[(size_t)r * DINNER + d]);
    float du = dt * ut;
    S += dt;
    const float* bc = xdbl + (size_t)r * 96 + 64;   // wave-uniform -> scalar loads
#pragma unroll
    for (int n = 0; n < 16; n++) {
      float dA = exp2f(dt * al2e[n]);
      h[n] = dA * h[n] + du * bc[n];
    }
  }
  size_t base = (((size_t)(b * NCHUNK + c) * DINNER) + d) * 16;
#pragma unroll
  for (int n = 0; n < 16; n++) hend[base + n] = h[n];
  Ssum[(b * NCHUNK + c) * DINNER + d] = S;
}

// ---------------- scan phase B: cross-chunk recurrence, Hin IN PLACE over hend ---------
__global__ void scanB(float* __restrict__ hend, const float* __restrict__ Ssum,
                      const float* __restrict__ A_log) {
  int g = blockIdx.x * 256 + threadIdx.x;   // 2*2048*16
  int n = g & 15, d = (g >> 4) & 2047, b = g >> 15;
  float al2e = -expf(A_log[d * 16 + n]) * LOG2E;
  float H = 0.f;
#pragma unroll
  for (int c = 0; c < NCHUNK; c++) {
    size_t idx = (((size_t)(b * NCHUNK + c) * DINNER) + d) * 16 + n;
    float he = hend[idx];
    float P = exp2f(Ssum[(b * NCHUNK + c) * DINNER + d] * al2e);
    hend[idx] = H;                                   // now holds H_in for chunk c
    H = P * H + he;
  }
}

// ---------------- scan phase C: full scan w/ correct h0, fused skip+gate ----------------
__global__ void scanC(const bf16* __restrict__ delta, const bf16* __restrict__ u,
                      const float* __restrict__ xdbl, const bf16* __restrict__ xzb,
                      const float* __restrict__ A_log, const float* __restrict__ Dv,
                      const float* __restrict__ Hin, bf16* __restrict__ yg) {
  int d = blockIdx.x * 256 + threadIdx.x;
  int c = blockIdx.y, b = blockIdx.z;
  float al2e[16];
#pragma unroll
  for (int n = 0; n < 16; n++)
    al2e[n] = -expf(A_log[d * 16 + n]) * LOG2E;
  float Dd = Dv[d];
  float h[16];
  size_t hb = (((size_t)(b * NCHUNK + c) * DINNER) + d) * 16;
#pragma unroll
  for (int n = 0; n < 16; n++) h[n] = Hin[hb + n];
  int t0 = c * CLEN;
  for (int t = t0; t < t0 + CLEN; ++t) {
    int r = b * 1024 + t;
    float dt = __bfloat162float(delta[(size_t)r * DINNER + d]);
    float ut = __bfloat162float(u[(size_t)r * DINNER + d]);
    float du = dt * ut;
    float z = __bfloat162float(xzb[(size_t)r * 4096 + 2048 + d]);
    const float* bc = xdbl + (size_t)r * 96 + 64;
    float y = 0.f;
#pragma unroll
    for (int n = 0; n < 16; n++) {
      float dA = exp2f(dt * al2e[n]);
      h[n] = dA * h[n] + du * bc[n];
      y += h[n] * bc[16 + n];
    }
    y += ut * Dd;
    y *= z / (1.f + expf(-z));                     // * silu(z)
    yg[(size_t)r * 4096 + d] = __float2bfloat16(y);
  }
}

extern "C" void kernel_launch(void* const* d_in, const int* in_sizes, int n_in,
                              void* d_out, int out_size, void* d_ws, size_t ws_size,
                              hipStream_t stream) {
  const void* x     = d_in[0];
  const void* W_in  = d_in[1];
  const void* ck    = d_in[2];
  const void* cb    = d_in[3];
  const void* W_x   = d_in[4];
  const void* W_dt  = d_in[5];
  const void* b_dt  = d_in[6];
  const void* W_out = d_in[7];
  const void* A_log = d_in[8];
  const void* Dv    = d_in[9];
  (void)in_sizes; (void)n_in; (void)out_size; (void)ws_size;

  char* w = (char*)d_ws;
  size_t off = 0;
  auto alloc = [&](size_t nb) { void* p = w + off; off += (nb + 255) & ~(size_t)255; return p; };

  int*   flag  = (int*)  alloc(256);
  float* ckF   = (float*)alloc((size_t)4 * 2048 * 4);
  float* cbF   = (float*)alloc((size_t)2048 * 4);
  float* bdtF  = (float*)alloc((size_t)2048 * 4);
  float* AlogF = (float*)alloc((size_t)2048 * 16 * 4);
  float* DF    = (float*)alloc((size_t)2048 * 4);
  bf16*  xb    = (bf16*) alloc((size_t)2048 * 1024 * 2);   // x bf16; reused as WoutT after GEMM1
  bf16*  WinT  = (bf16*) alloc((size_t)4096 * 1024 * 2);   // reused as delta after GEMM1
  bf16*  WxT   = (bf16*) alloc((size_t)96 * 2048 * 2);
  bf16*  WdtT  = (bf16*) alloc((size_t)2048 * 64 * 2);
  bf16*  xzb   = (bf16*) alloc((size_t)2048 * 4096 * 2);   // u-preact half reused as yg
  bf16*  u     = (bf16*) alloc((size_t)2048 * 2048 * 2);
  float* xdbl  = (float*)alloc((size_t)2048 * 96 * 4);
  bf16*  dt    = (bf16*) alloc((size_t)2048 * 64 * 2);
  float* hend  = (float*)alloc((size_t)2 * NCHUNK * 2048 * 16 * 4);  // ->pb ->Hin ->pb4
  float* Ssum  = (float*)alloc((size_t)2 * NCHUNK * 2048 * 4);
  // total ~46.5 MB

  bf16*  WoutT = xb;              // alias: dead after GEMM1
  bf16*  delta = WinT;            // alias: dead after GEMM1
  bf16*  yg    = xzb;             // alias: stride 4096, cols 0..2047 (dead after conv)
  float* pb2   = hend;            // alias: GEMM2 partials (12.6 MB), dead before scanA
  float* pb4   = hend;            // alias: GEMM4 partials (16 MB), Hin dead after scanC

  // --- dtype sniff + input canonicalization ---
  sniff<<<1, 256, 0, stream>>>(x, flag);
  cvt_params<<<184, 256, 0, stream>>>(flag, ck, cb, b_dt, A_log, Dv,
                                      ckF, cbF, bdtF, AlogF, DF);
  cvt_to_bf16<<<8192, 256, 0, stream>>>(flag, x, xb, 2048 * 1024);

  dim3 tb(32, 8);
  transpose_any<<<dim3(128, 32), tb, 0, stream>>>(flag, W_in, WinT, 1024, 4096);
  transpose_any<<<dim3(3, 64),   tb, 0, stream>>>(flag, W_x, WxT, 2048, 96);
  transpose_any<<<dim3(64, 2),   tb, 0, stream>>>(flag, W_dt, WdtT, 64, 2048);

  // GEMM1: xzb = x @ W_in  (bf16 out)
  gemm128<<<dim3(32, 16, 1), 256, 0, stream>>>(xb, WinT, 2048, 4096, 1024, 1024, 1024, 1,
                                               nullptr, xzb, nullptr, 0);
  // W_out^T into the now-dead xb region
  transpose_any<<<dim3(32, 64), tb, 0, stream>>>(flag, W_out, WoutT, 2048, 1024);
  // conv + SiLU -> u (bf16)
  conv_silu<<<dim3(8, 256), 256, 0, stream>>>(xzb, ckF, cbF, u);
  // GEMM2: x_dbl partials = u @ W_x  (N=96, split-K=16, plain slab stores)
  gemm128<<<dim3(1, 16, 16), 256, 0, stream>>>(u, WxT, 2048, 96, 2048, 2048, 2048, 16,
                                               pb2, nullptr, nullptr, 8);
  reduce_xdbl<<<768, 256, 0, stream>>>(pb2, xdbl, dt);
  // GEMM3: delta = softplus(dt_lo @ W_dt + b_dt)  (bf16 out into dead WinT)
  gemm128<<<dim3(16, 16, 1), 256, 0, stream>>>(dt, WdtT, 2048, 2048, 64, 64, 64, 1,
                                               nullptr, delta, bdtF, 1);
  // chunked selective scan
  scanA<<<dim3(8, NCHUNK, 2), 256, 0, stream>>>(delta, u, xdbl, AlogF, hend, Ssum);
  scanB<<<256, 256, 0, stream>>>(hend, Ssum, AlogF);
  scanC<<<dim3(8, NCHUNK, 2), 256, 0, stream>>>(delta, u, xdbl, xzb, AlogF, DF, hend, yg);
  // GEMM4: out partials = y_gated @ W_out  (split-K=2, plain slab stores into dead hend)
  gemm128<<<dim3(8, 16, 2), 256, 0, stream>>>(yg, WoutT, 2048, 1024, 2048, 4096, 2048, 2,
                                              pb4, nullptr, nullptr, 8);
  reduce_out<<<8192, 256, 0, stream>>>(flag, pb4, d_out);
}

// Round 5
// 299.599 us; speedup vs baseline: 1.1125x; 1.0846x over previous
//
#include <hip/hip_runtime.h>
#include <hip/hip_bf16.h>
#include <math.h>

typedef __hip_bfloat16 bf16;
typedef __bf16 bf16x8 __attribute__((ext_vector_type(8)));
typedef float floatx4 __attribute__((ext_vector_type(4)));

#define LOG2E 1.44269504088896340736f
#define DINNER 2048
#define NCHUNK 32
#define CLEN 32   // SEQ / NCHUNK

static __device__ __forceinline__ void gl_lds16(const void* g, void* l) {
  __builtin_amdgcn_global_load_lds(
      (const __attribute__((address_space(1))) void*)g,
      (__attribute__((address_space(3))) void*)l, 16, 0, 0);
}

// ---------------- 32x32 transpose tile: dst[C][R](bf16) = src[R][C](fp32) ----------------
static __device__ __forceinline__ void tr32(const float* __restrict__ src,
                                            bf16* __restrict__ dst, int R, int C,
                                            int tile, bf16 (*t)[33]) {
  int ctiles = C >> 5;
  int c0 = (tile % ctiles) << 5, r0 = (tile / ctiles) << 5;
  int tx = threadIdx.x & 31, ty = threadIdx.x >> 5;   // 32 x 8
#pragma unroll
  for (int i = 0; i < 4; i++)
    t[ty + i * 8][tx] = __float2bfloat16(src[(size_t)(r0 + ty + i * 8) * C + c0 + tx]);
  __syncthreads();
#pragma unroll
  for (int i = 0; i < 4; i++)
    dst[(size_t)(c0 + ty + i * 8) * R + r0 + tx] = t[tx][ty + i * 8];
}

// prep1: W_in^T, W_x^T, W_dt^T transposes + x -> bf16.  grid = 4096+192+128+1024 = 5440
__global__ void prep1(const float* __restrict__ W_in, const float* __restrict__ W_x,
                      const float* __restrict__ W_dt, const float* __restrict__ x,
                      bf16* __restrict__ WinT, bf16* __restrict__ WxT,
                      bf16* __restrict__ WdtT, bf16* __restrict__ xb) {
  __shared__ bf16 t[32][33];
  int b = blockIdx.x;
  if (b < 4096) { tr32(W_in, WinT, 1024, 4096, b, t); return; }
  b -= 4096;
  if (b < 192)  { tr32(W_x, WxT, 2048, 96, b, t); return; }
  b -= 192;
  if (b < 128)  { tr32(W_dt, WdtT, 64, 2048, b, t); return; }
  b -= 128;
  int base = b * 2048 + threadIdx.x;   // 1024 blocks x 2048 elems
#pragma unroll
  for (int i = 0; i < 8; i++)
    xb[base + i * 256] = __float2bfloat16(x[base + i * 256]);
}

// prep2: W_out^T into the (dead after GEMM1) xb region.  grid = 2048
__global__ void prep2(const float* __restrict__ W_out, bf16* __restrict__ WoutT) {
  __shared__ bf16 t[32][33];
  tr32(W_out, WoutT, 2048, 1024, blockIdx.x, t);
}

// ---------------- 128x128 MFMA GEMM, single-buffered (m97 structure) ----------------
// A: MxK rowmajor(lda), Bt: NxK rowmajor(ldb)
// flags: 1 = softplus(+bias) epilogue; 8 = partial store outF + z*M*N (split-K slabs)
__global__ __launch_bounds__(256, 2)
void gemm128(const bf16* __restrict__ A, const bf16* __restrict__ Bt,
             int M, int N, int K, int lda, int ldb, int ksplit,
             float* __restrict__ outF, bf16* __restrict__ outB,
             const float* __restrict__ bias, int flags) {
  __shared__ bf16 As[128 * 32];
  __shared__ bf16 Bs[128 * 32];
  const int tid = threadIdx.x;
  const int wave = tid >> 6, lane = tid & 63;
  const int wm = wave & 1, wn = wave >> 1;
  const int m0 = blockIdx.y * 128, n0 = blockIdx.x * 128;
  const int kper = K / ksplit;
  const int kbeg = blockIdx.z * kper, kend = kbeg + kper;

  floatx4 acc[4][4];
#pragma unroll
  for (int i = 0; i < 4; i++)
#pragma unroll
    for (int j = 0; j < 4; j++) acc[i][j] = (floatx4){0.f, 0.f, 0.f, 0.f};

  const int ch0 = wave * 2, ch1 = wave * 2 + 1;
  const int srow = lane >> 2;         // 0..15
  const int skcol = (lane & 3) * 8;   // 0,8,16,24
  const int fr = lane & 15, quad = lane >> 4;

  const int ra0 = m0 + ch0 * 16 + srow;
  const int ra1 = m0 + ch1 * 16 + srow;
  int rb0 = n0 + ch0 * 16 + srow; if (rb0 > N - 1) rb0 = N - 1;  // clamp (N=96 case)
  int rb1 = n0 + ch1 * 16 + srow; if (rb1 > N - 1) rb1 = N - 1;

  for (int k0 = kbeg; k0 < kend; k0 += 32) {
    __syncthreads();
    gl_lds16(A + (size_t)ra0 * lda + k0 + skcol, (char*)As + ch0 * 1024 + lane * 16);
    gl_lds16(A + (size_t)ra1 * lda + k0 + skcol, (char*)As + ch1 * 1024 + lane * 16);
    gl_lds16(Bt + (size_t)rb0 * ldb + k0 + skcol, (char*)Bs + ch0 * 1024 + lane * 16);
    gl_lds16(Bt + (size_t)rb1 * ldb + k0 + skcol, (char*)Bs + ch1 * 1024 + lane * 16);
    __syncthreads();
    bf16x8 af[4], bfr[4];
#pragma unroll
    for (int i = 0; i < 4; i++)
      af[i] = *reinterpret_cast<const bf16x8*>(&As[(wm * 64 + i * 16 + fr) * 32 + quad * 8]);
#pragma unroll
    for (int j = 0; j < 4; j++)
      bfr[j] = *reinterpret_cast<const bf16x8*>(&Bs[(wn * 64 + j * 16 + fr) * 32 + quad * 8]);
#pragma unroll
    for (int i = 0; i < 4; i++)
#pragma unroll
      for (int j = 0; j < 4; j++)
        acc[i][j] = __builtin_amdgcn_mfma_f32_16x16x32_bf16(af[i], bfr[j], acc[i][j], 0, 0, 0);
  }

  // epilogue: C/D layout col=lane&15, row=quad*4+r
#pragma unroll
  for (int i = 0; i < 4; i++) {
#pragma unroll
    for (int j = 0; j < 4; j++) {
      int col = n0 + wn * 64 + j * 16 + fr;
      if (col >= N) continue;
#pragma unroll
      for (int r = 0; r < 4; r++) {
        int row = m0 + wm * 64 + i * 16 + quad * 4 + r;
        float v = acc[i][j][r];
        if (flags & 8) {
          outF[(size_t)blockIdx.z * M * N + (size_t)row * N + col] = v;
        } else {
          if (bias) v += bias[col];
          if (flags & 1) v = (v > 20.f) ? v : log1pf(expf(v));  // softplus
          if (outF) outF[(size_t)row * N + col] = v;
          if (outB) outB[(size_t)row * N + col] = __float2bfloat16(v);
        }
      }
    }
  }
}

// ---------------- causal depthwise conv (k=4) + bias + SiLU ----------------
__global__ void conv_silu(const bf16* __restrict__ xzb, const float* __restrict__ ck,
                          const float* __restrict__ cb, bf16* __restrict__ u) {
  int d = blockIdx.x * 256 + threadIdx.x;
  int r0 = blockIdx.y * 8;          // 8 rows per block-row; 1024%8==0 so no batch crossing
  int t0 = r0 & 1023;
  float k0 = ck[0 * DINNER + d];
  float k1 = ck[1 * DINNER + d];
  float k2 = ck[2 * DINNER + d];
  float k3 = ck[3 * DINNER + d];
  float bias = cb[d];
  float in[11];
#pragma unroll
  for (int i = 0; i < 11; i++) {
    int t = t0 - 3 + i;
    in[i] = (t >= 0) ? __bfloat162float(xzb[(size_t)(r0 - 3 + i) * 4096 + d]) : 0.f;
  }
#pragma unroll
  for (int i = 0; i < 8; i++) {
    float v = bias + in[i] * k0 + in[i + 1] * k1 + in[i + 2] * k2 + in[i + 3] * k3;
    v = v / (1.f + expf(-v));       // SiLU
    u[(size_t)(r0 + i) * DINNER + d] = __float2bfloat16(v);
  }
}

// ---------------- reduce 16 split-K slabs -> xdbl fp32 + dt bf16 ----------------
__global__ void reduce_xdbl(const float* __restrict__ pb, float* __restrict__ xdbl,
                            bf16* __restrict__ dt) {
  int g = blockIdx.x * 256 + threadIdx.x;   // 2048*96
  float s = 0.f;
#pragma unroll
  for (int z = 0; z < 16; z++) s += pb[(size_t)z * 2048 * 96 + g];
  xdbl[g] = s;
  int r = g / 96, j = g - r * 96;
  if (j < 64) dt[r * 64 + j] = __float2bfloat16(s);
}

// ---------------- reduce 2 slabs -> final fp32 output ----------------
__global__ void reduce_out(const float* __restrict__ pb, float* __restrict__ out) {
  int g = blockIdx.x * 256 + threadIdx.x;   // 2048*1024
  out[g] = pb[g] + pb[2048 * 1024 + g];
}

// ---------------- scan phase A: per-chunk local h_end + sum(delta) ----------------
__global__ void scanA(const bf16* __restrict__ delta, const bf16* __restrict__ u,
                      const float* __restrict__ xdbl, const float* __restrict__ A_log,
                      float* __restrict__ hend, float* __restrict__ Ssum) {
  int d = blockIdx.x * 256 + threadIdx.x;
  int c = blockIdx.y, b = blockIdx.z;
  float al2e[16];
#pragma unroll
  for (int n = 0; n < 16; n++)
    al2e[n] = -expf(A_log[d * 16 + n]) * LOG2E;
  float h[16];
#pragma unroll
  for (int n = 0; n < 16; n++) h[n] = 0.f;
  float S = 0.f;
  int t0 = c * CLEN;
  for (int t = t0; t < t0 + CLEN; ++t) {
    int r = b * 1024 + t;
    float dt = __bfloat162float(delta[(size_t)r * DINNER + d]);
    float ut = __bfloat162float(u[(size_t)r * DINNER + d]);
    float du = dt * ut;
    S += dt;
    const float* bc = xdbl + (size_t)r * 96 + 64;   // wave-uniform -> scalar loads
#pragma unroll
    for (int n = 0; n < 16; n++) {
      float dA = exp2f(dt * al2e[n]);
      h[n] = dA * h[n] + du * bc[n];
    }
  }
  size_t base = (((size_t)(b * NCHUNK + c) * DINNER) + d) * 16;
#pragma unroll
  for (int n = 0; n < 16; n++) hend[base + n] = h[n];
  Ssum[(b * NCHUNK + c) * DINNER + d] = S;
}

// ---------------- scan phase B: cross-chunk recurrence, Hin IN PLACE over hend ---------
__global__ void scanB(float* __restrict__ hend, const float* __restrict__ Ssum,
                      const float* __restrict__ A_log) {
  int g = blockIdx.x * 256 + threadIdx.x;   // 2*2048*16
  int n = g & 15, d = (g >> 4) & 2047, b = g >> 15;
  float al2e = -expf(A_log[d * 16 + n]) * LOG2E;
  float H = 0.f;
#pragma unroll
  for (int c = 0; c < NCHUNK; c++) {
    size_t idx = (((size_t)(b * NCHUNK + c) * DINNER) + d) * 16 + n;
    float he = hend[idx];
    float P = exp2f(Ssum[(b * NCHUNK + c) * DINNER + d] * al2e);
    hend[idx] = H;                                   // now holds H_in for chunk c
    H = P * H + he;
  }
}

// ---------------- scan phase C: full scan w/ correct h0, fused skip+gate ----------------
__global__ void scanC(const bf16* __restrict__ delta, const bf16* __restrict__ u,
                      const float* __restrict__ xdbl, const bf16* __restrict__ xzb,
                      const float* __restrict__ A_log, const float* __restrict__ Dv,
                      const float* __restrict__ Hin, bf16* __restrict__ yg) {
  int d = blockIdx.x * 256 + threadIdx.x;
  int c = blockIdx.y, b = blockIdx.z;
  float al2e[16];
#pragma unroll
  for (int n = 0; n < 16; n++)
    al2e[n] = -expf(A_log[d * 16 + n]) * LOG2E;
  float Dd = Dv[d];
  float h[16];
  size_t hb = (((size_t)(b * NCHUNK + c) * DINNER) + d) * 16;
#pragma unroll
  for (int n = 0; n < 16; n++) h[n] = Hin[hb + n];
  int t0 = c * CLEN;
  for (int t = t0; t < t0 + CLEN; ++t) {
    int r = b * 1024 + t;
    float dt = __bfloat162float(delta[(size_t)r * DINNER + d]);
    float ut = __bfloat162float(u[(size_t)r * DINNER + d]);
    float du = dt * ut;
    float z = __bfloat162float(xzb[(size_t)r * 4096 + 2048 + d]);
    const float* bc = xdbl + (size_t)r * 96 + 64;
    float y = 0.f;
#pragma unroll
    for (int n = 0; n < 16; n++) {
      float dA = exp2f(dt * al2e[n]);
      h[n] = dA * h[n] + du * bc[n];
      y += h[n] * bc[16 + n];
    }
    y += ut * Dd;
    y *= z / (1.f + expf(-z));                     // * silu(z)
    yg[(size_t)r * 4096 + d] = __float2bfloat16(y);
  }
}

extern "C" void kernel_launch(void* const* d_in, const int* in_sizes, int n_in,
                              void* d_out, int out_size, void* d_ws, size_t ws_size,
                              hipStream_t stream) {
  const float* x     = (const float*)d_in[0];
  const float* W_in  = (const float*)d_in[1];
  const float* ck    = (const float*)d_in[2];
  const float* cb    = (const float*)d_in[3];
  const float* W_x   = (const float*)d_in[4];
  const float* W_dt  = (const float*)d_in[5];
  const float* b_dt  = (const float*)d_in[6];
  const float* W_out = (const float*)d_in[7];
  const float* A_log = (const float*)d_in[8];
  const float* Dv    = (const float*)d_in[9];
  float* out = (float*)d_out;
  (void)in_sizes; (void)n_in; (void)out_size; (void)ws_size;

  char* w = (char*)d_ws;
  size_t off = 0;
  auto alloc = [&](size_t nb) { void* p = w + off; off += (nb + 255) & ~(size_t)255; return p; };

  bf16*  WinT  = (bf16*) alloc((size_t)4096 * 1024 * 2);   // reused as delta after GEMM1
  bf16*  WxT   = (bf16*) alloc((size_t)96 * 2048 * 2);
  bf16*  WdtT  = (bf16*) alloc((size_t)2048 * 64 * 2);
  bf16*  xb    = (bf16*) alloc((size_t)2048 * 1024 * 2);   // x bf16 -> WoutT after GEMM1
  bf16*  xzb   = (bf16*) alloc((size_t)2048 * 4096 * 2);   // u-preact half reused as yg
  bf16*  u     = (bf16*) alloc((size_t)2048 * 2048 * 2);
  float* xdbl  = (float*)alloc((size_t)2048 * 96 * 4);
  bf16*  dt    = (bf16*) alloc((size_t)2048 * 64 * 2);
  float* hend  = (float*)alloc((size_t)2 * NCHUNK * 2048 * 16 * 4);  // ->pb2 ->Hin ->pb4
  float* Ssum  = (float*)alloc((size_t)2 * NCHUNK * 2048 * 4);
  // total ~54.2 MB

  bf16*  WoutT = xb;              // alias: dead after GEMM1
  bf16*  delta = WinT;            // alias: dead after GEMM1
  bf16*  yg    = xzb;             // alias: stride 4096, cols 0..2047 (dead after conv)
  float* pb2   = hend;            // alias: GEMM2 partials (12.6 MB), dead before scanA
  float* pb4   = hend;            // alias: GEMM4 partials (16.8 MB), Hin dead after scanC

  // prep1: W_in/W_x/W_dt transposes + x->bf16
  prep1<<<5440, 256, 0, stream>>>(W_in, W_x, W_dt, x, WinT, WxT, WdtT, xb);
  // GEMM1: xzb = x @ W_in  (bf16 out)
  gemm128<<<dim3(32, 16, 1), 256, 0, stream>>>(xb, WinT, 2048, 4096, 1024, 1024, 1024, 1,
                                               nullptr, xzb, nullptr, 0);
  // prep2: W_out^T into the now-dead xb region
  prep2<<<2048, 256, 0, stream>>>(W_out, WoutT);
  // conv + SiLU -> u (bf16)
  conv_silu<<<dim3(8, 256), 256, 0, stream>>>(xzb, ck, cb, u);
  // GEMM2: x_dbl partials = u @ W_x  (N=96, split-K=16, 4 iters/block, slab stores)
  gemm128<<<dim3(1, 16, 16), 256, 0, stream>>>(u, WxT, 2048, 96, 2048, 2048, 2048, 16,
                                               pb2, nullptr, nullptr, 8);
  reduce_xdbl<<<768, 256, 0, stream>>>(pb2, xdbl, dt);
  // GEMM3: delta = softplus(dt_lo @ W_dt + b_dt)  (bf16 out into dead WinT)
  gemm128<<<dim3(16, 16, 1), 256, 0, stream>>>(dt, WdtT, 2048, 2048, 64, 64, 64, 1,
                                               nullptr, delta, b_dt, 1);
  // chunked selective scan
  scanA<<<dim3(8, NCHUNK, 2), 256, 0, stream>>>(delta, u, xdbl, A_log, hend, Ssum);
  scanB<<<256, 256, 0, stream>>>(hend, Ssum, A_log);
  scanC<<<dim3(8, NCHUNK, 2), 256, 0, stream>>>(delta, u, xdbl, xzb, A_log, Dv, hend, yg);
  // GEMM4: out partials = y_gated @ W_out  (split-K=2, slab stores into dead hend)
  gemm128<<<dim3(8, 16, 2), 256, 0, stream>>>(yg, WoutT, 2048, 1024, 2048, 4096, 2048, 2,
                                              pb4, nullptr, nullptr, 8);
  reduce_out<<<8192, 256, 0, stream>>>(pb4, out);
}

// Round 6
// 291.540 us; speedup vs baseline: 1.1432x; 1.0276x over previous
//
#include <hip/hip_runtime.h>
#include <hip/hip_bf16.h>
#include <math.h>

typedef __hip_bfloat16 bf16;
typedef __bf16 bf16x8 __attribute__((ext_vector_type(8)));
typedef float floatx4 __attribute__((ext_vector_type(4)));

#define LOG2E 1.44269504088896340736f
#define DINNER 2048
#define NCHUNK 32
#define CLEN 32   // SEQ / NCHUNK

static __device__ __forceinline__ void gl_lds16(const void* g, void* l) {
  __builtin_amdgcn_global_load_lds(
      (const __attribute__((address_space(1))) void*)g,
      (__attribute__((address_space(3))) void*)l, 16, 0, 0);
}

// ---------------- 32x32 transpose tile: dst[C][R](bf16) = src[R][C](fp32) ----------------
static __device__ __forceinline__ void tr32(const float* __restrict__ src,
                                            bf16* __restrict__ dst, int R, int C,
                                            int tile, bf16 (*t)[33]) {
  int ctiles = C >> 5;
  int c0 = (tile % ctiles) << 5, r0 = (tile / ctiles) << 5;
  int tx = threadIdx.x & 31, ty = threadIdx.x >> 5;   // 32 x 8
#pragma unroll
  for (int i = 0; i < 4; i++)
    t[ty + i * 8][tx] = __float2bfloat16(src[(size_t)(r0 + ty + i * 8) * C + c0 + tx]);
  __syncthreads();
#pragma unroll
  for (int i = 0; i < 4; i++)
    dst[(size_t)(c0 + ty + i * 8) * R + r0 + tx] = t[tx][ty + i * 8];
}

// prep1: W_in^T, W_x^T, W_dt^T transposes + x -> bf16.  grid = 4096+192+128+1024 = 5440
__global__ void prep1(const float* __restrict__ W_in, const float* __restrict__ W_x,
                      const float* __restrict__ W_dt, const float* __restrict__ x,
                      bf16* __restrict__ WinT, bf16* __restrict__ WxT,
                      bf16* __restrict__ WdtT, bf16* __restrict__ xb) {
  __shared__ bf16 t[32][33];
  int b = blockIdx.x;
  if (b < 4096) { tr32(W_in, WinT, 1024, 4096, b, t); return; }
  b -= 4096;
  if (b < 192)  { tr32(W_x, WxT, 2048, 96, b, t); return; }
  b -= 192;
  if (b < 128)  { tr32(W_dt, WdtT, 64, 2048, b, t); return; }
  b -= 128;
  int base = b * 2048 + threadIdx.x;   // 1024 blocks x 2048 elems
#pragma unroll
  for (int i = 0; i < 8; i++)
    xb[base + i * 256] = __float2bfloat16(x[base + i * 256]);
}

// prep2: W_out^T into the (dead after GEMM1) xb region.  grid = 2048
__global__ void prep2(const float* __restrict__ W_out, bf16* __restrict__ WoutT) {
  __shared__ bf16 t[32][33];
  tr32(W_out, WoutT, 2048, 1024, blockIdx.x, t);
}

// ---------------- 128x128 MFMA GEMM, BK=64, XOR-swizzled LDS ----------------
// A: MxK rowmajor(lda), Bt: NxK rowmajor(ldb).  K%64==0, kper%64==0.
// flags: 1 = softplus(+bias) epilogue; 8 = partial store outF + z*M*N (split-K slabs)
__global__ __launch_bounds__(256, 2)
void gemm128(const bf16* __restrict__ A, const bf16* __restrict__ Bt,
             int M, int N, int K, int lda, int ldb, int ksplit,
             float* __restrict__ outF, bf16* __restrict__ outB,
             const float* __restrict__ bias, int flags) {
  __shared__ bf16 As[128 * 64];
  __shared__ bf16 Bs[128 * 64];
  const int tid = threadIdx.x;
  const int wave = tid >> 6, lane = tid & 63;
  const int wm = wave & 1, wn = wave >> 1;
  const int m0 = blockIdx.y * 128, n0 = blockIdx.x * 128;
  const int kper = K / ksplit;
  const int kbeg = blockIdx.z * kper, kend = kbeg + kper;

  floatx4 acc[4][4];
#pragma unroll
  for (int i = 0; i < 4; i++)
#pragma unroll
    for (int j = 0; j < 4; j++) acc[i][j] = (floatx4){0.f, 0.f, 0.f, 0.f};

  const int fr = lane & 15, quad = lane >> 4;
  // staging: 16 groups of 8 rows; wave w stages groups w*4..w*4+3
  const int lrow = lane >> 3;                 // 0..7 row within group
  const int slot = lane & 7;                  // LDS 16B slot within row
  const int kchunk = slot ^ lrow;             // XOR swizzle: slot s holds chunk s^(r&7)
  const int kcol = kchunk * 8;                // k offset in elements

  for (int k0 = kbeg; k0 < kend; k0 += 64) {
    __syncthreads();
#pragma unroll
    for (int g = 0; g < 4; g++) {
      int grp = wave * 4 + g;
      int ra = m0 + grp * 8 + lrow;
      int rb = n0 + grp * 8 + lrow; if (rb > N - 1) rb = N - 1;   // clamp (N=96 case)
      gl_lds16(A + (size_t)ra * lda + k0 + kcol, (char*)As + grp * 1024 + lane * 16);
      gl_lds16(Bt + (size_t)rb * ldb + k0 + kcol, (char*)Bs + grp * 1024 + lane * 16);
    }
    __syncthreads();
#pragma unroll
    for (int ks = 0; ks < 2; ks++) {
      bf16x8 af[4], bfr[4];
#pragma unroll
      for (int i = 0; i < 4; i++) {
        int row = wm * 64 + i * 16 + fr;
        af[i] = *reinterpret_cast<const bf16x8*>(&As[row * 64 + (((ks * 4 + quad) ^ (row & 7)) * 8)]);
      }
#pragma unroll
      for (int j = 0; j < 4; j++) {
        int row = wn * 64 + j * 16 + fr;
        bfr[j] = *reinterpret_cast<const bf16x8*>(&Bs[row * 64 + (((ks * 4 + quad) ^ (row & 7)) * 8)]);
      }
#pragma unroll
      for (int i = 0; i < 4; i++)
#pragma unroll
        for (int j = 0; j < 4; j++)
          acc[i][j] = __builtin_amdgcn_mfma_f32_16x16x32_bf16(af[i], bfr[j], acc[i][j], 0, 0, 0);
    }
  }

  // epilogue: C/D layout col=lane&15, row=quad*4+r
#pragma unroll
  for (int i = 0; i < 4; i++) {
#pragma unroll
    for (int j = 0; j < 4; j++) {
      int col = n0 + wn * 64 + j * 16 + fr;
      if (col >= N) continue;
#pragma unroll
      for (int r = 0; r < 4; r++) {
        int row = m0 + wm * 64 + i * 16 + quad * 4 + r;
        float v = acc[i][j][r];
        if (flags & 8) {
          outF[(size_t)blockIdx.z * M * N + (size_t)row * N + col] = v;
        } else {
          if (bias) v += bias[col];
          if (flags & 1) v = (v > 20.f) ? v : log1pf(expf(v));  // softplus
          if (outF) outF[(size_t)row * N + col] = v;
          if (outB) outB[(size_t)row * N + col] = __float2bfloat16(v);
        }
      }
    }
  }
}

// ---------------- causal depthwise conv (k=4) + bias + SiLU ----------------
__global__ void conv_silu(const bf16* __restrict__ xzb, const float* __restrict__ ck,
                          const float* __restrict__ cb, bf16* __restrict__ u) {
  int d = blockIdx.x * 256 + threadIdx.x;
  int r0 = blockIdx.y * 8;          // 8 rows per block-row; 1024%8==0 so no batch crossing
  int t0 = r0 & 1023;
  float k0 = ck[0 * DINNER + d];
  float k1 = ck[1 * DINNER + d];
  float k2 = ck[2 * DINNER + d];
  float k3 = ck[3 * DINNER + d];
  float bias = cb[d];
  float in[11];
#pragma unroll
  for (int i = 0; i < 11; i++) {
    int t = t0 - 3 + i;
    in[i] = (t >= 0) ? __bfloat162float(xzb[(size_t)(r0 - 3 + i) * 4096 + d]) : 0.f;
  }
#pragma unroll
  for (int i = 0; i < 8; i++) {
    float v = bias + in[i] * k0 + in[i + 1] * k1 + in[i + 2] * k2 + in[i + 3] * k3;
    v = v / (1.f + expf(-v));       // SiLU
    u[(size_t)(r0 + i) * DINNER + d] = __float2bfloat16(v);
  }
}

// ---------------- reduce 16 split-K slabs -> xdbl fp32 + dt bf16 ----------------
__global__ void reduce_xdbl(const float* __restrict__ pb, float* __restrict__ xdbl,
                            bf16* __restrict__ dt) {
  int g = blockIdx.x * 256 + threadIdx.x;   // 2048*96
  float s = 0.f;
#pragma unroll
  for (int z = 0; z < 16; z++) s += pb[(size_t)z * 2048 * 96 + g];
  xdbl[g] = s;
  int r = g / 96, j = g - r * 96;
  if (j < 64) dt[r * 64 + j] = __float2bfloat16(s);
}

// ---------------- reduce 4 slabs -> final fp32 output ----------------
__global__ void reduce_out(const float* __restrict__ pb, float* __restrict__ out) {
  int g = blockIdx.x * 256 + threadIdx.x;   // 2048*1024
  const int S = 2048 * 1024;
  out[g] = (pb[g] + pb[S + g]) + (pb[2 * S + g] + pb[3 * S + g]);
}

// ---------------- scan phase A: per-chunk local h_end + sum(delta) ----------------
__global__ void scanA(const bf16* __restrict__ delta, const bf16* __restrict__ u,
                      const float* __restrict__ xdbl, const float* __restrict__ A_log,
                      float* __restrict__ hend, float* __restrict__ Ssum) {
  int d = blockIdx.x * 256 + threadIdx.x;
  int c = blockIdx.y, b = blockIdx.z;
  float al2e[16];
#pragma unroll
  for (int n = 0; n < 16; n++)
    al2e[n] = -expf(A_log[d * 16 + n]) * LOG2E;
  float h[16];
#pragma unroll
  for (int n = 0; n < 16; n++) h[n] = 0.f;
  float S = 0.f;
  int t0 = c * CLEN;
  for (int t = t0; t < t0 + CLEN; ++t) {
    int r = b * 1024 + t;
    float dt = __bfloat162float(delta[(size_t)r * DINNER + d]);
    float ut = __bfloat162float(u[(size_t)r * DINNER + d]);
    float du = dt * ut;
    S += dt;
    const float* bc = xdbl + (size_t)r * 96 + 64;   // wave-uniform -> scalar loads
#pragma unroll
    for (int n = 0; n < 16; n++) {
      float dA = exp2f(dt * al2e[n]);
      h[n] = dA * h[n] + du * bc[n];
    }
  }
  size_t base = (((size_t)(b * NCHUNK + c) * DINNER) + d) * 16;
#pragma unroll
  for (int n = 0; n < 16; n++) hend[base + n] = h[n];
  Ssum[(b * NCHUNK + c) * DINNER + d] = S;
}

// ---------------- scan phase B: cross-chunk recurrence, Hin IN PLACE over hend ---------
__global__ void scanB(float* __restrict__ hend, const float* __restrict__ Ssum,
                      const float* __restrict__ A_log) {
  int g = blockIdx.x * 256 + threadIdx.x;   // 2*2048*16
  int n = g & 15, d = (g >> 4) & 2047, b = g >> 15;
  float al2e = -expf(A_log[d * 16 + n]) * LOG2E;
  float H = 0.f;
#pragma unroll
  for (int c = 0; c < NCHUNK; c++) {
    size_t idx = (((size_t)(b * NCHUNK + c) * DINNER) + d) * 16 + n;
    float he = hend[idx];
    float P = exp2f(Ssum[(b * NCHUNK + c) * DINNER + d] * al2e);
    hend[idx] = H;                                   // now holds H_in for chunk c
    H = P * H + he;
  }
}

// ---------------- scan phase C: full scan w/ correct h0, fused skip+gate ----------------
__global__ void scanC(const bf16* __restrict__ delta, const bf16* __restrict__ u,
                      const float* __restrict__ xdbl, const bf16* __restrict__ xzb,
                      const float* __restrict__ A_log, const float* __restrict__ Dv,
                      const float* __restrict__ Hin, bf16* __restrict__ yg) {
  int d = blockIdx.x * 256 + threadIdx.x;
  int c = blockIdx.y, b = blockIdx.z;
  float al2e[16];
#pragma unroll
  for (int n = 0; n < 16; n++)
    al2e[n] = -expf(A_log[d * 16 + n]) * LOG2E;
  float Dd = Dv[d];
  float h[16];
  size_t hb = (((size_t)(b * NCHUNK + c) * DINNER) + d) * 16;
#pragma unroll
  for (int n = 0; n < 16; n++) h[n] = Hin[hb + n];
  int t0 = c * CLEN;
  for (int t = t0; t < t0 + CLEN; ++t) {
    int r = b * 1024 + t;
    float dt = __bfloat162float(delta[(size_t)r * DINNER + d]);
    float ut = __bfloat162float(u[(size_t)r * DINNER + d]);
    float du = dt * ut;
    float z = __bfloat162float(xzb[(size_t)r * 4096 + 2048 + d]);
    const float* bc = xdbl + (size_t)r * 96 + 64;
    float y = 0.f;
#pragma unroll
    for (int n = 0; n < 16; n++) {
      float dA = exp2f(dt * al2e[n]);
      h[n] = dA * h[n] + du * bc[n];
      y += h[n] * bc[16 + n];
    }
    y += ut * Dd;
    y *= z / (1.f + expf(-z));                     // * silu(z)
    yg[(size_t)r * 4096 + d] = __float2bfloat16(y);
  }
}

extern "C" void kernel_launch(void* const* d_in, const int* in_sizes, int n_in,
                              void* d_out, int out_size, void* d_ws, size_t ws_size,
                              hipStream_t stream) {
  const float* x     = (const float*)d_in[0];
  const float* W_in  = (const float*)d_in[1];
  const float* ck    = (const float*)d_in[2];
  const float* cb    = (const float*)d_in[3];
  const float* W_x   = (const float*)d_in[4];
  const float* W_dt  = (const float*)d_in[5];
  const float* b_dt  = (const float*)d_in[6];
  const float* W_out = (const float*)d_in[7];
  const float* A_log = (const float*)d_in[8];
  const float* Dv    = (const float*)d_in[9];
  float* out = (float*)d_out;
  (void)in_sizes; (void)n_in; (void)out_size; (void)ws_size;

  char* w = (char*)d_ws;
  size_t off = 0;
  auto alloc = [&](size_t nb) { void* p = w + off; off += (nb + 255) & ~(size_t)255; return p; };

  bf16*  WinT  = (bf16*) alloc((size_t)4096 * 1024 * 2);   // reused as delta after GEMM1
  bf16*  WxT   = (bf16*) alloc((size_t)96 * 2048 * 2);
  bf16*  WdtT  = (bf16*) alloc((size_t)2048 * 64 * 2);
  bf16*  xb    = (bf16*) alloc((size_t)2048 * 1024 * 2);   // x bf16 -> WoutT after GEMM1
  bf16*  xzb   = (bf16*) alloc((size_t)2048 * 4096 * 2);   // u-preact half reused as yg
  bf16*  u     = (bf16*) alloc((size_t)2048 * 2048 * 2);
  float* xdbl  = (float*)alloc((size_t)2048 * 96 * 4);
  bf16*  dt    = (bf16*) alloc((size_t)2048 * 64 * 2);
  float* hend  = (float*)alloc((size_t)2 * NCHUNK * 2048 * 16 * 4);  // ->pb2 ->Hin
  float* Ssum  = (float*)alloc((size_t)2 * NCHUNK * 2048 * 4);
  float* pb4   = (float*)alloc((size_t)4 * 2048 * 1024 * 4);   // GEMM4 split-K partials
  // total ~88 MB

  bf16*  WoutT = xb;              // alias: dead after GEMM1
  bf16*  delta = WinT;            // alias: dead after GEMM1
  bf16*  yg    = xzb;             // alias: stride 4096, cols 0..2047 (dead after conv)
  float* pb2   = hend;            // alias: GEMM2 partials (12.6 MB), dead before scanA

  // prep1: W_in/W_x/W_dt transposes + x->bf16
  prep1<<<5440, 256, 0, stream>>>(W_in, W_x, W_dt, x, WinT, WxT, WdtT, xb);
  // GEMM1: xzb = x @ W_in  (bf16 out), 16 k-iters
  gemm128<<<dim3(32, 16, 1), 256, 0, stream>>>(xb, WinT, 2048, 4096, 1024, 1024, 1024, 1,
                                               nullptr, xzb, nullptr, 0);
  // prep2: W_out^T into the now-dead xb region
  prep2<<<2048, 256, 0, stream>>>(W_out, WoutT);
  // conv + SiLU -> u (bf16)
  conv_silu<<<dim3(8, 256), 256, 0, stream>>>(xzb, ck, cb, u);
  // GEMM2: x_dbl partials = u @ W_x  (N=96, split-K=16, 2 iters/block, slab stores)
  gemm128<<<dim3(1, 16, 16), 256, 0, stream>>>(u, WxT, 2048, 96, 2048, 2048, 2048, 16,
                                               pb2, nullptr, nullptr, 8);
  reduce_xdbl<<<768, 256, 0, stream>>>(pb2, xdbl, dt);
  // GEMM3: delta = softplus(dt_lo @ W_dt + b_dt)  (bf16 out into dead WinT), 1 iter
  gemm128<<<dim3(16, 16, 1), 256, 0, stream>>>(dt, WdtT, 2048, 2048, 64, 64, 64, 1,
                                               nullptr, delta, b_dt, 1);
  // chunked selective scan
  scanA<<<dim3(8, NCHUNK, 2), 256, 0, stream>>>(delta, u, xdbl, A_log, hend, Ssum);
  scanB<<<256, 256, 0, stream>>>(hend, Ssum, A_log);
  scanC<<<dim3(8, NCHUNK, 2), 256, 0, stream>>>(delta, u, xdbl, xzb, A_log, Dv, hend, yg);
  // GEMM4: out partials = y_gated @ W_out  (split-K=4 -> 512 blocks, 8 iters each)
  gemm128<<<dim3(8, 16, 4), 256, 0, stream>>>(yg, WoutT, 2048, 1024, 2048, 4096, 2048, 4,
                                              pb4, nullptr, nullptr, 8);
  reduce_out<<<8192, 256, 0, stream>>>(pb4, out);
}

// Round 7
// 251.383 us; speedup vs baseline: 1.3259x; 1.1597x over previous
//
#include <hip/hip_runtime.h>
#include <hip/hip_bf16.h>
#include <math.h>

typedef __hip_bfloat16 bf16;
typedef __bf16 bf16x8 __attribute__((ext_vector_type(8)));
typedef float floatx4 __attribute__((ext_vector_type(4)));

#define LOG2E 1.44269504088896340736f
#define DINNER 2048
#define NCHUNK 32
#define CLEN 32   // SEQ / NCHUNK

static __device__ __forceinline__ void gl_lds16(const void* g, void* l) {
  __builtin_amdgcn_global_load_lds(
      (const __attribute__((address_space(1))) void*)g,
      (__attribute__((address_space(3))) void*)l, 16, 0, 0);
}

// ---------------- 32x32 transpose tile: dst[C][R](bf16) = src[R][C](fp32) ----------------
static __device__ __forceinline__ void tr32(const float* __restrict__ src,
                                            bf16* __restrict__ dst, int R, int C,
                                            int tile, bf16 (*t)[33]) {
  int ctiles = C >> 5;
  int c0 = (tile % ctiles) << 5, r0 = (tile / ctiles) << 5;
  int tx = threadIdx.x & 31, ty = threadIdx.x >> 5;   // 32 x 8
#pragma unroll
  for (int i = 0; i < 4; i++)
    t[ty + i * 8][tx] = __float2bfloat16(src[(size_t)(r0 + ty + i * 8) * C + c0 + tx]);
  __syncthreads();
#pragma unroll
  for (int i = 0; i < 4; i++)
    dst[(size_t)(c0 + ty + i * 8) * R + r0 + tx] = t[tx][ty + i * 8];
}

// prep1: all four W transposes + x -> bf16.  grid = 4096+192+128+2048+1024 = 7488
__global__ void prep1(const float* __restrict__ W_in, const float* __restrict__ W_x,
                      const float* __restrict__ W_dt, const float* __restrict__ W_out,
                      const float* __restrict__ x,
                      bf16* __restrict__ WinT, bf16* __restrict__ WxT,
                      bf16* __restrict__ WdtT, bf16* __restrict__ WoutT,
                      bf16* __restrict__ xb) {
  __shared__ bf16 t[32][33];
  int b = blockIdx.x;
  if (b < 4096) { tr32(W_in, WinT, 1024, 4096, b, t); return; }
  b -= 4096;
  if (b < 192)  { tr32(W_x, WxT, 2048, 96, b, t); return; }
  b -= 192;
  if (b < 128)  { tr32(W_dt, WdtT, 64, 2048, b, t); return; }
  b -= 128;
  if (b < 2048) { tr32(W_out, WoutT, 2048, 1024, b, t); return; }
  b -= 2048;
  int base = b * 2048 + threadIdx.x;   // 1024 blocks x 2048 elems
#pragma unroll
  for (int i = 0; i < 8; i++)
    xb[base + i * 256] = __float2bfloat16(x[base + i * 256]);
}

// ---------------- 128x64 MFMA GEMM, BK=64, XOR-swizzled LDS, 4 blocks/CU ----------------
// A: MxK rowmajor(lda), Bt: NxK rowmajor(ldb).  K%64==0, kper%64==0.
// flags: 1 = softplus(+bias) epilogue; 8 = partial store outF + z*M*N (split-K slabs)
__global__ __launch_bounds__(256, 4)
void gemm128(const bf16* __restrict__ A, const bf16* __restrict__ Bt,
             int M, int N, int K, int lda, int ldb, int ksplit,
             float* __restrict__ outF, bf16* __restrict__ outB,
             const float* __restrict__ bias, int flags) {
  __shared__ bf16 As[128 * 64];   // 16 KB
  __shared__ bf16 Bs[64 * 64];    //  8 KB
  const int tid = threadIdx.x;
  const int wave = tid >> 6, lane = tid & 63;
  const int wm = wave & 1, wn = wave >> 1;    // wave tile: 64(m) x 32(n)
  const int m0 = blockIdx.y * 128, n0 = blockIdx.x * 64;
  const int kper = K / ksplit;
  const int kbeg = blockIdx.z * kper, kend = kbeg + kper;

  floatx4 acc[4][2];
#pragma unroll
  for (int i = 0; i < 4; i++)
#pragma unroll
    for (int j = 0; j < 2; j++) acc[i][j] = (floatx4){0.f, 0.f, 0.f, 0.f};

  const int fr = lane & 15, quad = lane >> 4;
  // staging: groups of 8 rows; A has 16 groups, B has 8
  const int lrow = lane >> 3;                 // 0..7 row within group
  const int slot = lane & 7;                  // LDS 16B slot within row
  const int kcol = (slot ^ lrow) * 8;         // XOR swizzle source k-chunk

  for (int k0 = kbeg; k0 < kend; k0 += 64) {
    __syncthreads();
#pragma unroll
    for (int g = 0; g < 4; g++) {
      int grp = wave * 4 + g;
      int ra = m0 + grp * 8 + lrow;
      gl_lds16(A + (size_t)ra * lda + k0 + kcol, (char*)As + grp * 1024 + lane * 16);
    }
#pragma unroll
    for (int g = 0; g < 2; g++) {
      int grp = wave * 2 + g;
      int rb = n0 + grp * 8 + lrow; if (rb > N - 1) rb = N - 1;   // clamp (N=96 case)
      gl_lds16(Bt + (size_t)rb * ldb + k0 + kcol, (char*)Bs + grp * 1024 + lane * 16);
    }
    __syncthreads();
#pragma unroll
    for (int ks = 0; ks < 2; ks++) {
      bf16x8 af[4], bfr[2];
#pragma unroll
      for (int i = 0; i < 4; i++) {
        int row = wm * 64 + i * 16 + fr;
        af[i] = *reinterpret_cast<const bf16x8*>(&As[row * 64 + (((ks * 4 + quad) ^ (row & 7)) * 8)]);
      }
#pragma unroll
      for (int j = 0; j < 2; j++) {
        int row = wn * 32 + j * 16 + fr;
        bfr[j] = *reinterpret_cast<const bf16x8*>(&Bs[row * 64 + (((ks * 4 + quad) ^ (row & 7)) * 8)]);
      }
#pragma unroll
      for (int i = 0; i < 4; i++)
#pragma unroll
        for (int j = 0; j < 2; j++)
          acc[i][j] = __builtin_amdgcn_mfma_f32_16x16x32_bf16(af[i], bfr[j], acc[i][j], 0, 0, 0);
    }
  }

  // epilogue: C/D layout col=lane&15, row=quad*4+r
#pragma unroll
  for (int i = 0; i < 4; i++) {
#pragma unroll
    for (int j = 0; j < 2; j++) {
      int col = n0 + wn * 32 + j * 16 + fr;
      if (col >= N) continue;
#pragma unroll
      for (int r = 0; r < 4; r++) {
        int row = m0 + wm * 64 + i * 16 + quad * 4 + r;
        float v = acc[i][j][r];
        if (flags & 8) {
          outF[(size_t)blockIdx.z * M * N + (size_t)row * N + col] = v;
        } else {
          if (bias) v += bias[col];
          if (flags & 1) v = (v > 20.f) ? v : log1pf(expf(v));  // softplus
          if (outF) outF[(size_t)row * N + col] = v;
          if (outB) outB[(size_t)row * N + col] = __float2bfloat16(v);
        }
      }
    }
  }
}

// ---------------- causal depthwise conv (k=4) + bias + SiLU ----------------
__global__ void conv_silu(const bf16* __restrict__ xzb, const float* __restrict__ ck,
                          const float* __restrict__ cb, bf16* __restrict__ u) {
  int d = blockIdx.x * 256 + threadIdx.x;
  int r0 = blockIdx.y * 8;          // 8 rows per block-row; 1024%8==0 so no batch crossing
  int t0 = r0 & 1023;
  float k0 = ck[0 * DINNER + d];
  float k1 = ck[1 * DINNER + d];
  float k2 = ck[2 * DINNER + d];
  float k3 = ck[3 * DINNER + d];
  float bias = cb[d];
  float in[11];
#pragma unroll
  for (int i = 0; i < 11; i++) {
    int t = t0 - 3 + i;
    in[i] = (t >= 0) ? __bfloat162float(xzb[(size_t)(r0 - 3 + i) * 4096 + d]) : 0.f;
  }
#pragma unroll
  for (int i = 0; i < 8; i++) {
    float v = bias + in[i] * k0 + in[i + 1] * k1 + in[i + 2] * k2 + in[i + 3] * k3;
    v = v / (1.f + expf(-v));       // SiLU
    u[(size_t)(r0 + i) * DINNER + d] = __float2bfloat16(v);
  }
}

// ---------------- reduce 8 split-K slabs -> xdbl fp32 + dt bf16 ----------------
__global__ void reduce_xdbl(const float* __restrict__ pb, float* __restrict__ xdbl,
                            bf16* __restrict__ dt) {
  int g = blockIdx.x * 256 + threadIdx.x;   // 2048*96
  float s = 0.f;
#pragma unroll
  for (int z = 0; z < 8; z++) s += pb[(size_t)z * 2048 * 96 + g];
  xdbl[g] = s;
  int r = g / 96, j = g - r * 96;
  if (j < 64) dt[r * 64 + j] = __float2bfloat16(s);
}

// ---------------- reduce 4 slabs -> final fp32 output ----------------
__global__ void reduce_out(const float* __restrict__ pb, float* __restrict__ out) {
  int g = blockIdx.x * 256 + threadIdx.x;   // 2048*1024
  const int S = 2048 * 1024;
  out[g] = (pb[g] + pb[S + g]) + (pb[2 * S + g] + pb[3 * S + g]);
}

// ---------------- scan phase A: per-chunk local h_end + sum(delta) ----------------
__global__ void scanA(const bf16* __restrict__ delta, const bf16* __restrict__ u,
                      const float* __restrict__ xdbl, const float* __restrict__ A_log,
                      float* __restrict__ hend, float* __restrict__ Ssum) {
  int d = blockIdx.x * 256 + threadIdx.x;
  int c = blockIdx.y, b = blockIdx.z;
  float al2e[16];
#pragma unroll
  for (int n = 0; n < 16; n++)
    al2e[n] = -expf(A_log[d * 16 + n]) * LOG2E;
  float h[16];
#pragma unroll
  for (int n = 0; n < 16; n++) h[n] = 0.f;
  float S = 0.f;
  int t0 = c * CLEN;
  for (int t = t0; t < t0 + CLEN; ++t) {
    int r = b * 1024 + t;
    float dt = __bfloat162float(delta[(size_t)r * DINNER + d]);
    float ut = __bfloat162float(u[(size_t)r * DINNER + d]);
    float du = dt * ut;
    S += dt;
    const float* bc = xdbl + (size_t)r * 96 + 64;   // wave-uniform -> scalar loads
#pragma unroll
    for (int n = 0; n < 16; n++) {
      float dA = exp2f(dt * al2e[n]);
      h[n] = dA * h[n] + du * bc[n];
    }
  }
  size_t base = (((size_t)(b * NCHUNK + c) * DINNER) + d) * 16;
#pragma unroll
  for (int n = 0; n < 16; n++) hend[base + n] = h[n];
  Ssum[(b * NCHUNK + c) * DINNER + d] = S;
}

// ---------------- scan phase B: cross-chunk recurrence, Hin IN PLACE over hend ---------
__global__ void scanB(float* __restrict__ hend, const float* __restrict__ Ssum,
                      const float* __restrict__ A_log) {
  int g = blockIdx.x * 256 + threadIdx.x;   // 2*2048*16
  int n = g & 15, d = (g >> 4) & 2047, b = g >> 15;
  float al2e = -expf(A_log[d * 16 + n]) * LOG2E;
  float H = 0.f;
#pragma unroll
  for (int c = 0; c < NCHUNK; c++) {
    size_t idx = (((size_t)(b * NCHUNK + c) * DINNER) + d) * 16 + n;
    float he = hend[idx];
    float P = exp2f(Ssum[(b * NCHUNK + c) * DINNER + d] * al2e);
    hend[idx] = H;                                   // now holds H_in for chunk c
    H = P * H + he;
  }
}

// ---------------- scan phase C: full scan w/ correct h0, fused skip+gate ----------------
__global__ void scanC(const bf16* __restrict__ delta, const bf16* __restrict__ u,
                      const float* __restrict__ xdbl, const bf16* __restrict__ xzb,
                      const float* __restrict__ A_log, const float* __restrict__ Dv,
                      const float* __restrict__ Hin, bf16* __restrict__ yg) {
  int d = blockIdx.x * 256 + threadIdx.x;
  int c = blockIdx.y, b = blockIdx.z;
  float al2e[16];
#pragma unroll
  for (int n = 0; n < 16; n++)
    al2e[n] = -expf(A_log[d * 16 + n]) * LOG2E;
  float Dd = Dv[d];
  float h[16];
  size_t hb = (((size_t)(b * NCHUNK + c) * DINNER) + d) * 16;
#pragma unroll
  for (int n = 0; n < 16; n++) h[n] = Hin[hb + n];
  int t0 = c * CLEN;
  for (int t = t0; t < t0 + CLEN; ++t) {
    int r = b * 1024 + t;
    float dt = __bfloat162float(delta[(size_t)r * DINNER + d]);
    float ut = __bfloat162float(u[(size_t)r * DINNER + d]);
    float du = dt * ut;
    float z = __bfloat162float(xzb[(size_t)r * 4096 + 2048 + d]);
    const float* bc = xdbl + (size_t)r * 96 + 64;
    float y = 0.f;
#pragma unroll
    for (int n = 0; n < 16; n++) {
      float dA = exp2f(dt * al2e[n]);
      h[n] = dA * h[n] + du * bc[n];
      y += h[n] * bc[16 + n];
    }
    y += ut * Dd;
    y *= z / (1.f + expf(-z));                     // * silu(z)
    yg[(size_t)r * 4096 + d] = __float2bfloat16(y);
  }
}

extern "C" void kernel_launch(void* const* d_in, const int* in_sizes, int n_in,
                              void* d_out, int out_size, void* d_ws, size_t ws_size,
                              hipStream_t stream) {
  const float* x     = (const float*)d_in[0];
  const float* W_in  = (const float*)d_in[1];
  const float* ck    = (const float*)d_in[2];
  const float* cb    = (const float*)d_in[3];
  const float* W_x   = (const float*)d_in[4];
  const float* W_dt  = (const float*)d_in[5];
  const float* b_dt  = (const float*)d_in[6];
  const float* W_out = (const float*)d_in[7];
  const float* A_log = (const float*)d_in[8];
  const float* Dv    = (const float*)d_in[9];
  float* out = (float*)d_out;
  (void)in_sizes; (void)n_in; (void)out_size; (void)ws_size;

  char* w = (char*)d_ws;
  size_t off = 0;
  auto alloc = [&](size_t nb) { void* p = w + off; off += (nb + 255) & ~(size_t)255; return p; };

  bf16*  WinT  = (bf16*) alloc((size_t)4096 * 1024 * 2);   // reused as delta after GEMM1
  bf16*  WxT   = (bf16*) alloc((size_t)96 * 2048 * 2);
  bf16*  WdtT  = (bf16*) alloc((size_t)2048 * 64 * 2);
  bf16*  WoutT = (bf16*) alloc((size_t)1024 * 2048 * 2);
  bf16*  xb    = (bf16*) alloc((size_t)2048 * 1024 * 2);
  bf16*  xzb   = (bf16*) alloc((size_t)2048 * 4096 * 2);   // u-preact half reused as yg
  bf16*  u     = (bf16*) alloc((size_t)2048 * 2048 * 2);
  float* xdbl  = (float*)alloc((size_t)2048 * 96 * 4);
  bf16*  dt    = (bf16*) alloc((size_t)2048 * 64 * 2);
  float* hend  = (float*)alloc((size_t)2 * NCHUNK * 2048 * 16 * 4);  // ->pb2 ->Hin
  float* Ssum  = (float*)alloc((size_t)2 * NCHUNK * 2048 * 4);
  float* pb4   = (float*)alloc((size_t)4 * 2048 * 1024 * 4);   // GEMM4 split-K partials
  // total ~92 MB (ws is 256 MB)

  bf16*  delta = WinT;            // alias: dead after GEMM1 (8 MB == 8 MB)
  bf16*  yg    = xzb;             // alias: stride 4096, cols 0..2047 (dead after conv)
  float* pb2   = hend;            // alias: GEMM2 partials (6.3 MB), dead before scanA

  // prep1: all W transposes + x->bf16
  prep1<<<7488, 256, 0, stream>>>(W_in, W_x, W_dt, W_out, x, WinT, WxT, WdtT, WoutT, xb);
  // GEMM1: xzb = x @ W_in  (bf16 out), grid 1024 = 4 blocks/CU, 16 k-iters
  gemm128<<<dim3(64, 16, 1), 256, 0, stream>>>(xb, WinT, 2048, 4096, 1024, 1024, 1024, 1,
                                               nullptr, xzb, nullptr, 0);
  // conv + SiLU -> u (bf16)
  conv_silu<<<dim3(8, 256), 256, 0, stream>>>(xzb, ck, cb, u);
  // GEMM2: x_dbl partials = u @ W_x  (N=96, split-K=8 -> 256 blocks, 4 iters)
  gemm128<<<dim3(2, 16, 8), 256, 0, stream>>>(u, WxT, 2048, 96, 2048, 2048, 2048, 8,
                                              pb2, nullptr, nullptr, 8);
  reduce_xdbl<<<768, 256, 0, stream>>>(pb2, xdbl, dt);
  // GEMM3: delta = softplus(dt_lo @ W_dt + b_dt)  (bf16 out into dead WinT), 512 blocks
  gemm128<<<dim3(32, 16, 1), 256, 0, stream>>>(dt, WdtT, 2048, 2048, 64, 64, 64, 1,
                                               nullptr, delta, b_dt, 1);
  // chunked selective scan
  scanA<<<dim3(8, NCHUNK, 2), 256, 0, stream>>>(delta, u, xdbl, A_log, hend, Ssum);
  scanB<<<256, 256, 0, stream>>>(hend, Ssum, A_log);
  scanC<<<dim3(8, NCHUNK, 2), 256, 0, stream>>>(delta, u, xdbl, xzb, A_log, Dv, hend, yg);
  // GEMM4: out partials = y_gated @ W_out  (split-K=4 -> 1024 blocks, 8 iters)
  gemm128<<<dim3(16, 16, 4), 256, 0, stream>>>(yg, WoutT, 2048, 1024, 2048, 4096, 2048, 4,
                                               pb4, nullptr, nullptr, 8);
  reduce_out<<<8192, 256, 0, stream>>>(pb4, out);
}

// Round 8
// 237.116 us; speedup vs baseline: 1.4056x; 1.0602x over previous
//
#include <hip/hip_runtime.h>
#include <hip/hip_bf16.h>
#include <math.h>

typedef __hip_bfloat16 bf16;
typedef __bf16 bf16x8 __attribute__((ext_vector_type(8)));
typedef float floatx4 __attribute__((ext_vector_type(4)));

#define LOG2E 1.44269504088896340736f
#define DINNER 2048
#define NCHUNK 32
#define CLEN 32   // SEQ / NCHUNK

static __device__ __forceinline__ void gl_lds16(const void* g, void* l) {
  __builtin_amdgcn_global_load_lds(
      (const __attribute__((address_space(1))) void*)g,
      (__attribute__((address_space(3))) void*)l, 16, 0, 0);
}

// ---------------- 32x32 transpose tile: dst[C][R](bf16) = src[R][C](fp32) ----------------
static __device__ __forceinline__ void tr32(const float* __restrict__ src,
                                            bf16* __restrict__ dst, int R, int C,
                                            int tile, bf16 (*t)[33]) {
  int ctiles = C >> 5;
  int c0 = (tile % ctiles) << 5, r0 = (tile / ctiles) << 5;
  int tx = threadIdx.x & 31, ty = threadIdx.x >> 5;   // 32 x 8
#pragma unroll
  for (int i = 0; i < 4; i++)
    t[ty + i * 8][tx] = __float2bfloat16(src[(size_t)(r0 + ty + i * 8) * C + c0 + tx]);
  __syncthreads();
#pragma unroll
  for (int i = 0; i < 4; i++)
    dst[(size_t)(c0 + ty + i * 8) * R + r0 + tx] = t[tx][ty + i * 8];
}

// prep1: all four W transposes + x -> bf16.  grid = 4096+192+128+2048+1024 = 7488
__global__ void prep1(const float* __restrict__ W_in, const float* __restrict__ W_x,
                      const float* __restrict__ W_dt, const float* __restrict__ W_out,
                      const float* __restrict__ x,
                      bf16* __restrict__ WinT, bf16* __restrict__ WxT,
                      bf16* __restrict__ WdtT, bf16* __restrict__ WoutT,
                      bf16* __restrict__ xb) {
  __shared__ bf16 t[32][33];
  int b = blockIdx.x;
  if (b < 4096) { tr32(W_in, WinT, 1024, 4096, b, t); return; }
  b -= 4096;
  if (b < 192)  { tr32(W_x, WxT, 2048, 96, b, t); return; }
  b -= 192;
  if (b < 128)  { tr32(W_dt, WdtT, 64, 2048, b, t); return; }
  b -= 128;
  if (b < 2048) { tr32(W_out, WoutT, 2048, 1024, b, t); return; }
  b -= 2048;
  int base = b * 2048 + threadIdx.x;   // 1024 blocks x 2048 elems
#pragma unroll
  for (int i = 0; i < 8; i++)
    xb[base + i * 256] = __float2bfloat16(x[base + i * 256]);
}

// ---------------- 128x64 MFMA GEMM, BK=64, XOR-swizzled LDS, 4 blocks/CU ----------------
// A: MxK rowmajor(lda), Bt: NxK rowmajor(ldb).  K%64==0, kper%64==0.
// flags: 1 = softplus(+bias) epilogue; 8 = partial store outF + z*M*N (split-K slabs)
// outB path requires N%64==0 (full tiles) and writes via LDS-staged coalesced stores.
__global__ __launch_bounds__(256, 4)
void gemm128(const bf16* __restrict__ A, const bf16* __restrict__ Bt,
             int M, int N, int K, int lda, int ldb, int ksplit,
             float* __restrict__ outF, bf16* __restrict__ outB,
             const float* __restrict__ bias, int flags) {
  __shared__ char smem[24576];               // As 16 KB | Bs 8 KB; reused as Cs (18.4 KB)
  bf16* As = (bf16*)smem;
  bf16* Bs = (bf16*)(smem + 16384);
  const int tid = threadIdx.x;
  const int wave = tid >> 6, lane = tid & 63;
  const int wm = wave & 1, wn = wave >> 1;    // wave tile: 64(m) x 32(n)
  const int m0 = blockIdx.y * 128, n0 = blockIdx.x * 64;
  const int kper = K / ksplit;
  const int kbeg = blockIdx.z * kper, kend = kbeg + kper;

  floatx4 acc[4][2];
#pragma unroll
  for (int i = 0; i < 4; i++)
#pragma unroll
    for (int j = 0; j < 2; j++) acc[i][j] = (floatx4){0.f, 0.f, 0.f, 0.f};

  const int fr = lane & 15, quad = lane >> 4;
  // staging: groups of 8 rows; A has 16 groups, B has 8
  const int lrow = lane >> 3;                 // 0..7 row within group
  const int slot = lane & 7;                  // LDS 16B slot within row
  const int kcol = (slot ^ lrow) * 8;         // XOR swizzle source k-chunk

  for (int k0 = kbeg; k0 < kend; k0 += 64) {
    __syncthreads();
#pragma unroll
    for (int g = 0; g < 4; g++) {
      int grp = wave * 4 + g;
      int ra = m0 + grp * 8 + lrow;
      gl_lds16(A + (size_t)ra * lda + k0 + kcol, (char*)As + grp * 1024 + lane * 16);
    }
#pragma unroll
    for (int g = 0; g < 2; g++) {
      int grp = wave * 2 + g;
      int rb = n0 + grp * 8 + lrow; if (rb > N - 1) rb = N - 1;   // clamp (N=96 case)
      gl_lds16(Bt + (size_t)rb * ldb + k0 + kcol, (char*)Bs + grp * 1024 + lane * 16);
    }
    __syncthreads();
#pragma unroll
    for (int ks = 0; ks < 2; ks++) {
      bf16x8 af[4], bfr[2];
#pragma unroll
      for (int i = 0; i < 4; i++) {
        int row = wm * 64 + i * 16 + fr;
        af[i] = *reinterpret_cast<const bf16x8*>(&As[row * 64 + (((ks * 4 + quad) ^ (row & 7)) * 8)]);
      }
#pragma unroll
      for (int j = 0; j < 2; j++) {
        int row = wn * 32 + j * 16 + fr;
        bfr[j] = *reinterpret_cast<const bf16x8*>(&Bs[row * 64 + (((ks * 4 + quad) ^ (row & 7)) * 8)]);
      }
#pragma unroll
      for (int i = 0; i < 4; i++)
#pragma unroll
        for (int j = 0; j < 2; j++)
          acc[i][j] = __builtin_amdgcn_mfma_f32_16x16x32_bf16(af[i], bfr[j], acc[i][j], 0, 0, 0);
    }
  }

  // epilogue: C/D layout col=lane&15, row=quad*4+r
  if (outB) {
    // LDS-staged coalesced bf16 store (full tiles; N%64==0)
    __syncthreads();                          // everyone done reading As/Bs
    bf16* Cs = (bf16*)smem;                   // 128 x 64, stride 72 (bank-shift per row)
#pragma unroll
    for (int i = 0; i < 4; i++)
#pragma unroll
      for (int j = 0; j < 2; j++) {
        int col = wn * 32 + j * 16 + fr;
        float b = bias ? bias[n0 + col] : 0.f;
#pragma unroll
        for (int r = 0; r < 4; r++) {
          int row = wm * 64 + i * 16 + quad * 4 + r;
          float v = acc[i][j][r] + b;
          if (flags & 1) v = fmaxf(v, 0.f) + __logf(1.f + __expf(-fabsf(v)));  // softplus
          Cs[row * 72 + col] = __float2bfloat16(v);
        }
      }
    __syncthreads();
#pragma unroll
    for (int it = 0; it < 4; it++) {
      int e = it * 256 + tid;                 // 0..1023, 8 bf16 each
      int row = e >> 3, col = (e & 7) * 8;
      *reinterpret_cast<float4*>(&outB[(size_t)(m0 + row) * N + n0 + col]) =
          *reinterpret_cast<const float4*>(&Cs[row * 72 + col]);
    }
    return;
  }
#pragma unroll
  for (int i = 0; i < 4; i++) {
#pragma unroll
    for (int j = 0; j < 2; j++) {
      int col = n0 + wn * 32 + j * 16 + fr;
      if (col >= N) continue;
#pragma unroll
      for (int r = 0; r < 4; r++) {
        int row = m0 + wm * 64 + i * 16 + quad * 4 + r;
        float v = acc[i][j][r];
        if (flags & 8) {
          outF[(size_t)blockIdx.z * M * N + (size_t)row * N + col] = v;
        } else {
          if (bias) v += bias[col];
          if (flags & 1) v = fmaxf(v, 0.f) + __logf(1.f + __expf(-fabsf(v)));
          outF[(size_t)row * N + col] = v;
        }
      }
    }
  }
}

// ---------------- causal depthwise conv (k=4) + bias + SiLU ----------------
__global__ void conv_silu(const bf16* __restrict__ xzb, const float* __restrict__ ck,
                          const float* __restrict__ cb, bf16* __restrict__ u) {
  int d = blockIdx.x * 256 + threadIdx.x;
  int r0 = blockIdx.y * 8;          // 8 rows per block-row; 1024%8==0 so no batch crossing
  int t0 = r0 & 1023;
  float k0 = ck[0 * DINNER + d];
  float k1 = ck[1 * DINNER + d];
  float k2 = ck[2 * DINNER + d];
  float k3 = ck[3 * DINNER + d];
  float bias = cb[d];
  float in[11];
#pragma unroll
  for (int i = 0; i < 11; i++) {
    int t = t0 - 3 + i;
    in[i] = (t >= 0) ? __bfloat162float(xzb[(size_t)(r0 - 3 + i) * 4096 + d]) : 0.f;
  }
#pragma unroll
  for (int i = 0; i < 8; i++) {
    float v = bias + in[i] * k0 + in[i + 1] * k1 + in[i + 2] * k2 + in[i + 3] * k3;
    v = v / (1.f + __expf(-v));     // SiLU
    u[(size_t)(r0 + i) * DINNER + d] = __float2bfloat16(v);
  }
}

// ---------------- reduce 8 split-K slabs -> xdbl fp32 + dt bf16 ----------------
__global__ void reduce_xdbl(const float* __restrict__ pb, float* __restrict__ xdbl,
                            bf16* __restrict__ dt) {
  int g = blockIdx.x * 256 + threadIdx.x;   // 2048*96
  float s = 0.f;
#pragma unroll
  for (int z = 0; z < 8; z++) s += pb[(size_t)z * 2048 * 96 + g];
  xdbl[g] = s;
  int r = g / 96, j = g - r * 96;
  if (j < 64) dt[r * 64 + j] = __float2bfloat16(s);
}

// ---------------- reduce 4 slabs -> final fp32 output ----------------
__global__ void reduce_out(const float* __restrict__ pb, float* __restrict__ out) {
  int g = blockIdx.x * 256 + threadIdx.x;   // 2048*1024
  const int S = 2048 * 1024;
  out[g] = (pb[g] + pb[S + g]) + (pb[2 * S + g] + pb[3 * S + g]);
}

// ---------------- scan phase A: per-chunk local h_end + sum(delta) ----------------
__global__ void scanA(const bf16* __restrict__ delta, const bf16* __restrict__ u,
                      const float* __restrict__ xdbl, const float* __restrict__ A_log,
                      float* __restrict__ hend, float* __restrict__ Ssum) {
  int d = blockIdx.x * 256 + threadIdx.x;
  int c = blockIdx.y, b = blockIdx.z;
  float al2e[16];
#pragma unroll
  for (int n = 0; n < 16; n++)
    al2e[n] = -__expf(A_log[d * 16 + n]) * LOG2E;
  float h[16];
#pragma unroll
  for (int n = 0; n < 16; n++) h[n] = 0.f;
  float S = 0.f;
  int t0 = c * CLEN;
  for (int t = t0; t < t0 + CLEN; ++t) {
    int r = b * 1024 + t;
    float dt = __bfloat162float(delta[(size_t)r * DINNER + d]);
    float ut = __bfloat162float(u[(size_t)r * DINNER + d]);
    float du = dt * ut;
    S += dt;
    const float* bc = xdbl + (size_t)r * 96 + 64;   // wave-uniform -> scalar loads
#pragma unroll
    for (int n = 0; n < 16; n++) {
      float dA = exp2f(dt * al2e[n]);
      h[n] = dA * h[n] + du * bc[n];
    }
  }
  size_t base = (((size_t)(b * NCHUNK + c) * DINNER) + d) * 16;
#pragma unroll
  for (int n = 0; n < 16; n++) hend[base + n] = h[n];
  Ssum[(b * NCHUNK + c) * DINNER + d] = S;
}

// ---------------- scan phase B: cross-chunk recurrence, Hin IN PLACE over hend ---------
__global__ void scanB(float* __restrict__ hend, const float* __restrict__ Ssum,
                      const float* __restrict__ A_log) {
  int g = blockIdx.x * 256 + threadIdx.x;   // 2*2048*16
  int n = g & 15, d = (g >> 4) & 2047, b = g >> 15;
  float al2e = -__expf(A_log[d * 16 + n]) * LOG2E;
  float H = 0.f;
#pragma unroll
  for (int c = 0; c < NCHUNK; c++) {
    size_t idx = (((size_t)(b * NCHUNK + c) * DINNER) + d) * 16 + n;
    float he = hend[idx];
    float P = exp2f(Ssum[(b * NCHUNK + c) * DINNER + d] * al2e);
    hend[idx] = H;                                   // now holds H_in for chunk c
    H = P * H + he;
  }
}

// ---------------- scan phase C: full scan w/ correct h0, fused skip+gate ----------------
__global__ void scanC(const bf16* __restrict__ delta, const bf16* __restrict__ u,
                      const float* __restrict__ xdbl, const bf16* __restrict__ xzb,
                      const float* __restrict__ A_log, const float* __restrict__ Dv,
                      const float* __restrict__ Hin, bf16* __restrict__ yg) {
  int d = blockIdx.x * 256 + threadIdx.x;
  int c = blockIdx.y, b = blockIdx.z;
  float al2e[16];
#pragma unroll
  for (int n = 0; n < 16; n++)
    al2e[n] = -__expf(A_log[d * 16 + n]) * LOG2E;
  float Dd = Dv[d];
  float h[16];
  size_t hb = (((size_t)(b * NCHUNK + c) * DINNER) + d) * 16;
#pragma unroll
  for (int n = 0; n < 16; n++) h[n] = Hin[hb + n];
  int t0 = c * CLEN;
  for (int t = t0; t < t0 + CLEN; ++t) {
    int r = b * 1024 + t;
    float dt = __bfloat162float(delta[(size_t)r * DINNER + d]);
    float ut = __bfloat162float(u[(size_t)r * DINNER + d]);
    float du = dt * ut;
    float z = __bfloat162float(xzb[(size_t)r * 4096 + 2048 + d]);
    const float* bc = xdbl + (size_t)r * 96 + 64;
    float y = 0.f;
#pragma unroll
    for (int n = 0; n < 16; n++) {
      float dA = exp2f(dt * al2e[n]);
      h[n] = dA * h[n] + du * bc[n];
      y += h[n] * bc[16 + n];
    }
    y += ut * Dd;
    y *= z / (1.f + __expf(-z));                   // * silu(z)
    yg[(size_t)r * 4096 + d] = __float2bfloat16(y);
  }
}

extern "C" void kernel_launch(void* const* d_in, const int* in_sizes, int n_in,
                              void* d_out, int out_size, void* d_ws, size_t ws_size,
                              hipStream_t stream) {
  const float* x     = (const float*)d_in[0];
  const float* W_in  = (const float*)d_in[1];
  const float* ck    = (const float*)d_in[2];
  const float* cb    = (const float*)d_in[3];
  const float* W_x   = (const float*)d_in[4];
  const float* W_dt  = (const float*)d_in[5];
  const float* b_dt  = (const float*)d_in[6];
  const float* W_out = (const float*)d_in[7];
  const float* A_log = (const float*)d_in[8];
  const float* Dv    = (const float*)d_in[9];
  float* out = (float*)d_out;
  (void)in_sizes; (void)n_in; (void)out_size; (void)ws_size;

  char* w = (char*)d_ws;
  size_t off = 0;
  auto alloc = [&](size_t nb) { void* p = w + off; off += (nb + 255) & ~(size_t)255; return p; };

  bf16*  WinT  = (bf16*) alloc((size_t)4096 * 1024 * 2);   // reused as delta after GEMM1
  bf16*  WxT   = (bf16*) alloc((size_t)96 * 2048 * 2);
  bf16*  WdtT  = (bf16*) alloc((size_t)2048 * 64 * 2);
  bf16*  WoutT = (bf16*) alloc((size_t)1024 * 2048 * 2);
  bf16*  xb    = (bf16*) alloc((size_t)2048 * 1024 * 2);
  bf16*  xzb   = (bf16*) alloc((size_t)2048 * 4096 * 2);   // u-preact half reused as yg
  bf16*  u     = (bf16*) alloc((size_t)2048 * 2048 * 2);
  float* xdbl  = (float*)alloc((size_t)2048 * 96 * 4);
  bf16*  dt    = (bf16*) alloc((size_t)2048 * 64 * 2);
  float* hend  = (float*)alloc((size_t)2 * NCHUNK * 2048 * 16 * 4);  // ->pb2 ->Hin
  float* Ssum  = (float*)alloc((size_t)2 * NCHUNK * 2048 * 4);
  float* pb4   = (float*)alloc((size_t)4 * 2048 * 1024 * 4);   // GEMM4 split-K partials
  // total ~92 MB (ws is 256 MB)

  bf16*  delta = WinT;            // alias: dead after GEMM1 (8 MB == 8 MB)
  bf16*  yg    = xzb;             // alias: stride 4096, cols 0..2047 (dead after conv)
  float* pb2   = hend;            // alias: GEMM2 partials (6.3 MB), dead before scanA

  // prep1: all W transposes + x->bf16
  prep1<<<7488, 256, 0, stream>>>(W_in, W_x, W_dt, W_out, x, WinT, WxT, WdtT, WoutT, xb);
  // GEMM1: xzb = x @ W_in  (bf16 out), grid 1024 = 4 blocks/CU, 16 k-iters
  gemm128<<<dim3(64, 16, 1), 256, 0, stream>>>(xb, WinT, 2048, 4096, 1024, 1024, 1024, 1,
                                               nullptr, xzb, nullptr, 0);
  // conv + SiLU -> u (bf16)
  conv_silu<<<dim3(8, 256), 256, 0, stream>>>(xzb, ck, cb, u);
  // GEMM2: x_dbl partials = u @ W_x  (N=96, split-K=8 -> 256 blocks, 4 iters)
  gemm128<<<dim3(2, 16, 8), 256, 0, stream>>>(u, WxT, 2048, 96, 2048, 2048, 2048, 8,
                                              pb2, nullptr, nullptr, 8);
  reduce_xdbl<<<768, 256, 0, stream>>>(pb2, xdbl, dt);
  // GEMM3: delta = softplus(dt_lo @ W_dt + b_dt)  (bf16 out into dead WinT), 512 blocks
  gemm128<<<dim3(32, 16, 1), 256, 0, stream>>>(dt, WdtT, 2048, 2048, 64, 64, 64, 1,
                                               nullptr, delta, b_dt, 1);
  // chunked selective scan
  scanA<<<dim3(8, NCHUNK, 2), 256, 0, stream>>>(delta, u, xdbl, A_log, hend, Ssum);
  scanB<<<256, 256, 0, stream>>>(hend, Ssum, A_log);
  scanC<<<dim3(8, NCHUNK, 2), 256, 0, stream>>>(delta, u, xdbl, xzb, A_log, Dv, hend, yg);
  // GEMM4: out partials = y_gated @ W_out  (split-K=4 -> 1024 blocks, 8 iters)
  gemm128<<<dim3(16, 16, 4), 256, 0, stream>>>(yg, WoutT, 2048, 1024, 2048, 4096, 2048, 4,
                                               pb4, nullptr, nullptr, 8);
  reduce_out<<<8192, 256, 0, stream>>>(pb4, out);
}